// Round 3
// baseline (975.479 us; speedup 1.0000x reference)
//
#include <hip/hip_runtime.h>
#include <math.h>

#define NTOK 13824            // 24*24*24
#define MTOT 27648            // B*NTOK
#define BATCH 2
#define CIN 128
#define DMODEL 256
#define NHEAD 8
#define NLAYERS 4
#define DFF 512
#define NSPLIT 27
#define KVHALF ((size_t)BATCH * 256 * NTOK)

typedef float f32x4 __attribute__((ext_vector_type(4)));
typedef __bf16 bf16x8 __attribute__((ext_vector_type(8)));
typedef __attribute__((address_space(1))) void gvoid;
typedef __attribute__((address_space(3))) void lvoid;

// async global->LDS, 16B per lane. LDS dest must be uniform-base + lane*16.
#define GLDS16(g, l) __builtin_amdgcn_global_load_lds((gvoid*)(g), (lvoid*)(l), 16, 0, 0)

__device__ __forceinline__ unsigned short f2bf(float f) {
    unsigned u = __float_as_uint(f);
    return (unsigned short)((u + 0x7FFFu + ((u >> 16) & 1u)) >> 16);
}
__device__ __forceinline__ float bf2f(unsigned short h) {
    return __uint_as_float(((unsigned)h) << 16);
}

// ---------------------------------------------------------------------------
// bf16 MFMA GEMM, full-K-resident: C[M x N] = act(A[M x K](bf16) * B + bias)
// B supplied TRANSPOSED: Bt[N][K] bf16. 128x128 output tile, 256 threads.
// Whole K-panel (up to KT=256) of A and B lives in LDS: ONE deep staging
// burst (NP GLDS16 per thread per panel, all in flight together) + ONE
// barrier, then an uninterrupted 128-MFMA compute phase. No per-K-step
// barriers (K=256 -> 8 drains in the old structure, 1 here).
// G M-tiles per block reuse the resident B-panel; stage-A(g+1) is issued
// right after compute(g) and its latency hides under the C-epilogue.
// K=512 loops two 256-chunks (restages both panels per chunk).
// LDS rows are KT*2 bytes (512B = 16-way bank conflict raw); fixed via the
// m201 both-sides XOR: linear GLDS dest + XOR-pre-swizzled GLOBAL source +
// the same XOR on the ds_read index (involution: k ^= (row&7)*8 shorts).
// ACT: 0 none, 1 relu, 2 gelu(exact). OUTM: 1 = bf16 C only, 2 = f32 + bf16.
// ---------------------------------------------------------------------------
template<int ACT, int OUTM, int K, int G>
__global__ __launch_bounds__(256) void gemm_bf16(
    const unsigned short* __restrict__ A, int lda,
    const unsigned short* __restrict__ Bt, int ldb,
    const float* __restrict__ bias,
    float* __restrict__ Cf, unsigned short* __restrict__ Cb,
    int ldc, long sA, long sB, long sC)
{
    constexpr int KT  = (K < 256) ? K : 256;   // LDS-resident K-chunk
    constexpr int NKC = K / KT;                // chunks (1 or 2)
    constexpr int KSN = KT / 32;               // MFMA K-steps per chunk
    constexpr int CPR = KT / 8;                // 16B chunks per LDS row
    constexpr int RPP = 256 / CPR;             // rows staged per pass (4KB)
    constexpr int NP  = 128 / RPP;             // passes per 128-row panel

    A  += (size_t)blockIdx.z * sA;
    Bt += (size_t)blockIdx.z * sB;
    if (OUTM == 2) Cf += (size_t)blockIdx.z * sC;
    Cb += (size_t)blockIdx.z * sC;

    __shared__ __attribute__((aligned(16))) unsigned short As[128 * KT];
    __shared__ __attribute__((aligned(16))) unsigned short Bs[128 * KT];

    const int t    = threadIdx.x;
    const int lane = t & 63;
    const int wave = t >> 6;
    const int wm = wave & 1, wn = wave >> 1;
    const int n0 = blockIdx.y * 128;

    // staging map: pass p covers rows [p*RPP, (p+1)*RPP); thread row-in-pass
    // srow = t/CPR, 16B chunk = t%CPR. Source k pre-swizzled (involution
    // with the read-side XOR). row&7 == srow&7 (RPP multiple of 8).
    const int srow = t / CPR;
    const int sk   = ((t % CPR) * 8) ^ ((srow & 7) << 3);

    const int fm  = lane & 15;
    const int fq8 = (lane >> 4) * 8;
    const int sw3 = (fm & 7) << 3;             // read-side XOR (shorts)

    f32x4 acc[4][4];

    auto STAGE_A = [&](int m0, int kc) {
        #pragma unroll
        for (int p = 0; p < NP; ++p)
            GLDS16(A + (size_t)(m0 + p * RPP + srow) * lda + kc * KT + sk,
                   &As[p * 2048 + t * 8]);
    };
    auto STAGE_B = [&](int kc) {
        #pragma unroll
        for (int p = 0; p < NP; ++p)
            GLDS16(Bt + (size_t)(n0 + p * RPP + srow) * ldb + kc * KT + sk,
                   &Bs[p * 2048 + t * 8]);
    };
    auto COMPUTE = [&]() {
        #pragma unroll
        for (int ks = 0; ks < KSN; ++ks) {
            bf16x8 af[4], bg[4];
            const int kidx = (ks * 32 + fq8) ^ sw3;
            #pragma unroll
            for (int i = 0; i < 4; ++i)
                af[i] = *(const bf16x8*)(&As[(wm * 64 + i * 16 + fm) * KT + kidx]);
            #pragma unroll
            for (int j = 0; j < 4; ++j)
                bg[j] = *(const bf16x8*)(&Bs[(wn * 64 + j * 16 + fm) * KT + kidx]);
            #pragma unroll
            for (int i = 0; i < 4; ++i)
                #pragma unroll
                for (int j = 0; j < 4; ++j)
                    acc[i][j] = __builtin_amdgcn_mfma_f32_16x16x32_bf16(
                        af[i], bg[j], acc[i][j], 0, 0, 0);
        }
    };
    auto EPILOGUE = [&](int m0) {
        const int cb  = n0 + wn * 64 + fm;
        const int rbs = m0 + wm * 64 + (lane >> 4) * 4;
        #pragma unroll
        for (int j = 0; j < 4; ++j) {
            const int n = cb + j * 16;
            const float bv = bias[n];
            #pragma unroll
            for (int i = 0; i < 4; ++i) {
                #pragma unroll
                for (int r = 0; r < 4; ++r) {
                    float v = acc[i][j][r] + bv;
                    if (ACT == 1) v = fmaxf(v, 0.0f);
                    if (ACT == 2) v = 0.5f * v * (1.0f + erff(v * 0.7071067811865476f));
                    const size_t off = (size_t)(rbs + i * 16 + r) * ldc + n;
                    if (OUTM == 2) Cf[off] = v;
                    Cb[off] = f2bf(v);
                }
            }
        }
    };

    if constexpr (NKC == 1) {
        const int mb0 = blockIdx.x * (G * 128);
        STAGE_A(mb0, 0);
        STAGE_B(0);
        __syncthreads();                       // drains vmcnt: panels ready
        #pragma unroll
        for (int g = 0; g < G; ++g) {
            #pragma unroll
            for (int i = 0; i < 4; ++i)
                #pragma unroll
                for (int j = 0; j < 4; ++j) acc[i][j] = (f32x4)0.0f;
            COMPUTE();
            if (g + 1 < G) {
                __syncthreads();               // all waves done reading As
                STAGE_A(mb0 + (g + 1) * 128, 0);   // in flight under epilogue
            }
            EPILOGUE(mb0 + g * 128);
            if (g + 1 < G) __syncthreads();    // A(g+1) landed
        }
    } else {
        const int m0 = blockIdx.x * 128;       // G==1 for K>256
        #pragma unroll
        for (int i = 0; i < 4; ++i)
            #pragma unroll
            for (int j = 0; j < 4; ++j) acc[i][j] = (f32x4)0.0f;
        #pragma unroll
        for (int kc = 0; kc < NKC; ++kc) {
            if (kc) __syncthreads();           // prior reads done
            STAGE_A(m0, kc);
            STAGE_B(kc);
            __syncthreads();
            COMPUTE();
        }
        EPILOGUE(m0);
    }
}

// ---------------------------------------------------------------------------
// one-shot weight conversion: transpose to [N][K] bf16 + bias concat
// ---------------------------------------------------------------------------
#define CW_QKV  786432   // 4*768*256
#define CW_O   1048576   // + 4*256*256
#define CW_1   1572864   // + 4*512*256
#define CW_2   2097152   // + 4*256*512
#define CW_X   2129920   // + 256*128
#define CW_B   2132992   // + 4*768
__global__ __launch_bounds__(256) void conv_weights(
    const float* __restrict__ Wq, const float* __restrict__ Wk,
    const float* __restrict__ Wv, const float* __restrict__ Wo,
    const float* __restrict__ fw1, const float* __restrict__ fw2,
    const float* __restrict__ Wx_w,
    const float* __restrict__ bq, const float* __restrict__ bk,
    const float* __restrict__ bv,
    unsigned short* __restrict__ wqkv_t, unsigned short* __restrict__ wo_t,
    unsigned short* __restrict__ w1_t, unsigned short* __restrict__ w2_t,
    unsigned short* __restrict__ wx_bf, float* __restrict__ bqkv)
{
    const int e = blockIdx.x * 256 + threadIdx.x;
    if (e < CW_QKV) {
        const int i = e / 196608, r = e % 196608;
        const int n = r / 256, k = r % 256;
        const float* src = (n < 256) ? Wq : (n < 512) ? Wk : Wv;
        wqkv_t[e] = f2bf(src[((size_t)i * 256 + k) * 256 + (n & 255)]);
    } else if (e < CW_O) {
        const int r = e - CW_QKV;
        const int i = r / 65536, rr = r % 65536, n = rr / 256, k = rr % 256;
        wo_t[r] = f2bf(Wo[((size_t)i * 256 + k) * 256 + n]);
    } else if (e < CW_1) {
        const int r = e - CW_O;
        const int i = r / 131072, rr = r % 131072, n = rr / 256, k = rr % 256;
        w1_t[r] = f2bf(fw1[((size_t)i * 256 + k) * 512 + n]);
    } else if (e < CW_2) {
        const int r = e - CW_1;
        const int i = r / 131072, rr = r % 131072, n = rr / 512, k = rr % 512;
        w2_t[r] = f2bf(fw2[((size_t)i * 512 + k) * 256 + n]);
    } else if (e < CW_X) {
        const int r = e - CW_2;
        wx_bf[r] = f2bf(Wx_w[r]);     // Wx_w [out][in] is already B^T layout
    } else if (e < CW_B) {
        const int r = e - CW_X;
        const int i = r / 768, j = r % 768;
        const float v = (j < 256) ? bq[i * 256 + j]
                      : (j < 512) ? bk[i * 256 + j - 256]
                                  : bv[i * 256 + j - 512];
        bqkv[r] = v;
    }
}

// ---------------------------------------------------------------------------
// x [B][CIN][NTOK] f32 -> xbf [(b,n)][CIN] bf16, LDS 32x32 tile transpose.
// ---------------------------------------------------------------------------
__global__ __launch_bounds__(256) void conv_x(
    const float* __restrict__ x, unsigned short* __restrict__ xbf)
{
    __shared__ float tile[32][33];
    const int n0 = blockIdx.x * 32;
    const int c0 = blockIdx.y * 32;
    const int b  = blockIdx.z;
    const int t = threadIdx.x;
    const int tn = t & 31, tc = t >> 5;
    #pragma unroll
    for (int p = 0; p < 4; ++p)
        tile[tc + p * 8][tn] =
            x[((size_t)(b * CIN + c0 + tc + p * 8)) * NTOK + n0 + tn];
    __syncthreads();
    const int cc = t & 31, nr = t >> 5;
    #pragma unroll
    for (int p = 0; p < 4; ++p)
        xbf[((size_t)(b * NTOK + n0 + nr + p * 8)) * CIN + c0 + cc] =
            f2bf(tile[cc][nr + p * 8]);
}

// ---------------------------------------------------------------------------
// q softmax over dk=32, in place on the q-slot of qkv. 8 bf16 per lane.
// ---------------------------------------------------------------------------
__global__ __launch_bounds__(256) void qsm_kernel(unsigned short* __restrict__ qkv)
{
    const int g = blockIdx.x * 256 + threadIdx.x;   // < MTOT*32
    const int row = g >> 5;
    const int cg  = g & 31;                          // 8-channel chunk
    unsigned short* p = qkv + (size_t)row * 768 + cg * 8;
    uint4 raw = *(const uint4*)p;
    unsigned short* rp = (unsigned short*)&raw;
    float v[8];
    #pragma unroll
    for (int j = 0; j < 8; ++j) v[j] = bf2f(rp[j]);
    float m = v[0];
    #pragma unroll
    for (int j = 1; j < 8; ++j) m = fmaxf(m, v[j]);
    m = fmaxf(m, __shfl_xor(m, 1, 64));
    m = fmaxf(m, __shfl_xor(m, 2, 64));
    float s = 0.0f;
    #pragma unroll
    for (int j = 0; j < 8; ++j) { v[j] = __expf(v[j] - m); s += v[j]; }
    s += __shfl_xor(s, 1, 64);
    s += __shfl_xor(s, 2, 64);
    const float r = 1.0f / s;
    #pragma unroll
    for (int j = 0; j < 8; ++j) rp[j] = f2bf(v[j] * r);
    *(uint4*)p = raw;
}

// ---------------------------------------------------------------------------
// kvt: qkv k,v slots -> expkT/vT [b][ch][tok] bf16 (exp applied to k).
// grid (NTOK/64, NHEAD, B), block 256. LDS tile, coalesced both sides.
// kvT layout: [0, KVHALF) = expkT, [KVHALF, 2*KVHALF) = vT; row = b*256+ch.
// ---------------------------------------------------------------------------
__global__ __launch_bounds__(256) void kvt_kernel(
    const unsigned short* __restrict__ qkv, unsigned short* __restrict__ kvT)
{
    const int nb = blockIdx.x, h = blockIdx.y, b = blockIdx.z;
    const int n0 = nb * 64;
    const int t = threadIdx.x;
    __shared__ __attribute__((aligned(16))) unsigned short LT[64 * 72];
    const int tl = t >> 2, cg = t & 3;
    const unsigned short* src =
        qkv + ((size_t)(b * NTOK + n0 + tl)) * 768 + 256 + h * 32 + cg * 8;
    const uint4 kr = *(const uint4*)src;
    const uint4 vr = *(const uint4*)(src + 256);
    const unsigned short* ks = (const unsigned short*)&kr;
    const unsigned short* vs = (const unsigned short*)&vr;
    #pragma unroll
    for (int j = 0; j < 8; ++j) {
        const int ch = cg * 8 + j;
        LT[ch * 72 + tl]        = f2bf(__expf(bf2f(ks[j])));
        LT[(32 + ch) * 72 + tl] = vs[j];
    }
    __syncthreads();
    #pragma unroll
    for (int it = 0; it < 2; ++it) {
        const int idx = it * 256 + t;       // 0..511
        const int row = idx >> 3, seg = idx & 7;
        const uint4 val = *(const uint4*)(LT + row * 72 + seg * 8);
        const int ch = row & 31;
        const size_t dst = ((row >= 32) ? KVHALF : (size_t)0)
                         + ((size_t)(b * 256 + h * 32 + ch)) * NTOK + n0 + seg * 8;
        *(uint4*)(kvT + dst) = val;
    }
}

// ---------------------------------------------------------------------------
// ctx via MFMA, split-K, NO atomics.
// grid (NSPLIT, NHEAD, B), block 256 (4 waves). Each wave: 128 tokens,
// 16x16x32 MFMA, A = expkT rows (d), B = vT rows (e) -- direct global
// bf16x8 fragment loads (contiguous). Sk partials from A-frag sums.
// Outputs ctxp[s][b*8+h][1024], skp[s][b*256+ch].
// ---------------------------------------------------------------------------
__global__ __launch_bounds__(256) void ctx_mfma(
    const unsigned short* __restrict__ kvT,
    float* __restrict__ ctxp, float* __restrict__ skp)
{
    const int s = blockIdx.x, h = blockIdx.y, b = blockIdx.z;
    const int t = threadIdx.x, w = t >> 6, l = t & 63;
    const int fm = l & 15, fq = (l >> 4) * 8;
    const size_t rowA = (size_t)(b * 256 + h * 32 + fm) * NTOK;
    const int n0 = s * 512 + w * 128 + fq;
    const unsigned short* pa = kvT + rowA + n0;
    const unsigned short* pb = kvT + KVHALF + rowA + n0;

    f32x4 acc[2][2];
    #pragma unroll
    for (int x = 0; x < 2; ++x)
        #pragma unroll
        for (int y = 0; y < 2; ++y) acc[x][y] = (f32x4)0.0f;
    float ss0 = 0.0f, ss1 = 0.0f;

    #pragma unroll
    for (int step = 0; step < 4; ++step) {
        const int ko = step * 32;
        const uint4 ra0 = *(const uint4*)(pa + ko);
        const uint4 ra1 = *(const uint4*)(pa + (size_t)16 * NTOK + ko);
        const uint4 rb0 = *(const uint4*)(pb + ko);
        const uint4 rb1 = *(const uint4*)(pb + (size_t)16 * NTOK + ko);
        const bf16x8 a0 = *(const bf16x8*)&ra0;
        const bf16x8 a1 = *(const bf16x8*)&ra1;
        const bf16x8 b0 = *(const bf16x8*)&rb0;
        const bf16x8 b1 = *(const bf16x8*)&rb1;
        acc[0][0] = __builtin_amdgcn_mfma_f32_16x16x32_bf16(a0, b0, acc[0][0], 0, 0, 0);
        acc[0][1] = __builtin_amdgcn_mfma_f32_16x16x32_bf16(a0, b1, acc[0][1], 0, 0, 0);
        acc[1][0] = __builtin_amdgcn_mfma_f32_16x16x32_bf16(a1, b0, acc[1][0], 0, 0, 0);
        acc[1][1] = __builtin_amdgcn_mfma_f32_16x16x32_bf16(a1, b1, acc[1][1], 0, 0, 0);
        const unsigned short* u0 = (const unsigned short*)&ra0;
        const unsigned short* u1 = (const unsigned short*)&ra1;
        #pragma unroll
        for (int j = 0; j < 8; ++j) { ss0 += bf2f(u0[j]); ss1 += bf2f(u1[j]); }
    }

    // Sk: reduce over the 4 quads holding the same d
    ss0 += __shfl_xor(ss0, 16, 64); ss0 += __shfl_xor(ss0, 32, 64);
    ss1 += __shfl_xor(ss1, 16, 64); ss1 += __shfl_xor(ss1, 32, 64);
    __shared__ float skw[4][32];
    __shared__ float redc[4][32][33];
    if (l < 16) { skw[w][fm] = ss0; skw[w][16 + fm] = ss1; }

    // stage C tiles: row = x*16 + (l>>4)*4 + r, col = y*16 + fm
    const int rb4 = (l >> 4) * 4;
    #pragma unroll
    for (int x = 0; x < 2; ++x)
        #pragma unroll
        for (int y = 0; y < 2; ++y)
            #pragma unroll
            for (int r = 0; r < 4; ++r)
                redc[w][x * 16 + rb4 + r][y * 16 + fm] = acc[x][y][r];
    __syncthreads();

    if (t < 32)
        skp[(size_t)s * 512 + b * 256 + h * 32 + t] =
            skw[0][t] + skw[1][t] + skw[2][t] + skw[3][t];

    // 1024 outputs, 4 per thread
    const int e0 = t * 4;
    const int dd = e0 >> 5, c0 = e0 & 31;
    float4 o;
    o.x = redc[0][dd][c0+0] + redc[1][dd][c0+0] + redc[2][dd][c0+0] + redc[3][dd][c0+0];
    o.y = redc[0][dd][c0+1] + redc[1][dd][c0+1] + redc[2][dd][c0+1] + redc[3][dd][c0+1];
    o.z = redc[0][dd][c0+2] + redc[1][dd][c0+2] + redc[2][dd][c0+2] + redc[3][dd][c0+2];
    o.w = redc[0][dd][c0+3] + redc[1][dd][c0+3] + redc[2][dd][c0+3] + redc[3][dd][c0+3];
    *(float4*)(ctxp + ((size_t)s * 16 + b * 8 + h) * 1024 + e0) = o;
}

// reduce split-K partials: ctx[16][1024] and Sk[512]. grid 66 x 256.
__global__ __launch_bounds__(256) void ctxred(
    const float* __restrict__ ctxp, const float* __restrict__ skp,
    float* __restrict__ ctx, float* __restrict__ Sk)
{
    const int o = blockIdx.x * 256 + threadIdx.x;   // 0..16895
    if (o < 16384) {
        float a = 0.0f;
        for (int s = 0; s < NSPLIT; ++s) a += ctxp[(size_t)s * 16384 + o];
        ctx[o] = a;
    } else {
        const int c = o - 16384;
        float a = 0.0f;
        for (int s = 0; s < NSPLIT; ++s) a += skp[(size_t)s * 512 + c];
        Sk[c] = a;
    }
}

// ---------------------------------------------------------------------------
// W'[b][n][h*32+d] = (1/sqrt(dk)) * (1/Sk[d]) * sum_e ctx[b][h][d][e] * Wo[h*32+e][n]
// ---------------------------------------------------------------------------
__global__ __launch_bounds__(256) void ctxwo_kernel(
    const float* __restrict__ ctx, const float* __restrict__ Sk,
    const unsigned short* __restrict__ wo_t, unsigned short* __restrict__ wp)
{
    const int h = blockIdx.x, b = blockIdx.y;
    const int n = threadIdx.x;
    __shared__ float cl[1024];
    __shared__ float sdk[32];
    {
        const float* cp = ctx + (size_t)(b * 8 + h) * 1024;
        *(float4*)&cl[n * 4] = *(const float4*)&cp[n * 4];
    }
    if (n < 32) sdk[n] = 0.17677669529663687f / Sk[b * 256 + h * 32 + n];
    __syncthreads();
    float w[32];
    const unsigned short* wop = wo_t + (size_t)n * 256 + h * 32;
    #pragma unroll
    for (int e = 0; e < 32; ++e) w[e] = bf2f(wop[e]);
    unsigned short outv[32];
    #pragma unroll
    for (int d = 0; d < 32; ++d) {
        float acc = 0.0f;
        #pragma unroll
        for (int e = 0; e < 32; ++e) acc += cl[d * 32 + e] * w[e];
        outv[d] = f2bf(acc * sdk[d]);
    }
    unsigned short* op = wp + (size_t)b * 65536 + (size_t)n * 256 + h * 32;
    #pragma unroll
    for (int d = 0; d < 32; d += 8)
        *(uint4*)(op + d) = *(uint4*)(outv + d);
}

// ---------------------------------------------------------------------------
// t = LayerNorm(t + add(bf16)); writes t f32 in place (+ optional bf16 copy)
// ---------------------------------------------------------------------------
template<int WB>
__global__ __launch_bounds__(256) void ln_kernel(
    float* __restrict__ t, const unsigned short* __restrict__ add,
    const float* __restrict__ g, const float* __restrict__ bta,
    unsigned short* __restrict__ tbf)
{
    const int row = blockIdx.x;
    const int c = threadIdx.x;
    const int lane = c & 63, wave = c >> 6;
    const size_t off = (size_t)row * 256 + c;
    const float v = t[off] + bf2f(add[off]);
    __shared__ float red[8];
    float s = v;
    #pragma unroll
    for (int o = 32; o; o >>= 1) s += __shfl_xor(s, o, 64);
    if (lane == 0) red[wave] = s;
    __syncthreads();
    const float mu = (red[0] + red[1] + red[2] + red[3]) * (1.0f / 256.0f);
    const float dv = v - mu;
    float s2 = dv * dv;
    #pragma unroll
    for (int o = 32; o; o >>= 1) s2 += __shfl_xor(s2, o, 64);
    if (lane == 0) red[wave + 4] = s2;
    __syncthreads();
    const float var = (red[4] + red[5] + red[6] + red[7]) * (1.0f / 256.0f);
    const float o = dv * rsqrtf(var + 1e-6f) * g[c] + bta[c];
    t[off] = o;
    if (WB) tbf[off] = f2bf(o);
}

// ---------------------------------------------------------------------------
// depthwise 3x3x3 conv + residual, register-resident weights + sliding window.
// ---------------------------------------------------------------------------
template<int WB>
__global__ __launch_bounds__(256) void posconv_kernel(
    const float* __restrict__ tin, const float* __restrict__ pw,
    const float* __restrict__ pb, float* __restrict__ outp,
    unsigned short* __restrict__ tbfp)
{
    const int hw = blockIdx.x;            // 0..575
    const int b  = blockIdx.y;
    const int hh = hw / 24, ww = hw % 24;
    const int c  = threadIdx.x;

    float w[27];
    #pragma unroll
    for (int k = 0; k < 27; ++k) w[k] = pw[c * 27 + k];
    const float bias = pb[c];

    const float* base = tin + (size_t)b * NTOK * 256 + c;

    const float* colp[9];
    bool colok[9];
    #pragma unroll
    for (int dh = -1; dh <= 1; ++dh)
        #pragma unroll
        for (int dw = -1; dw <= 1; ++dw) {
            const int j = (dh + 1) * 3 + (dw + 1);
            const int h2 = hh + dh, w2 = ww + dw;
            colok[j] = ((unsigned)h2 < 24u) & ((unsigned)w2 < 24u);
            colp[j] = base + (size_t)((h2 * 24 + w2) * 24) * 256;
        }

    float win[9][3];
    #pragma unroll
    for (int j = 0; j < 9; ++j) {
        win[j][0] = 0.0f;
        win[j][1] = colok[j] ? colp[j][0] : 0.0f;
    }

    float* ob = outp + ((size_t)b * NTOK + (size_t)hw * 24) * 256 + c;
    unsigned short* tb = WB ? (tbfp + ((size_t)b * NTOK + (size_t)hw * 24) * 256 + c)
                            : (unsigned short*)nullptr;

    for (int d = 0; d < 24; ++d) {
        #pragma unroll
        for (int j = 0; j < 9; ++j)
            win[j][2] = (colok[j] && d < 23) ? colp[j][(d + 1) * 256] : 0.0f;

        float acc = bias + win[4][1];
        #pragma unroll
        for (int j = 0; j < 9; ++j) {
            acc += w[j * 3 + 0] * win[j][0];
            acc += w[j * 3 + 1] * win[j][1];
            acc += w[j * 3 + 2] * win[j][2];
        }
        ob[d * 256] = acc;
        if (WB) tb[d * 256] = f2bf(acc);

        #pragma unroll
        for (int j = 0; j < 9; ++j) { win[j][0] = win[j][1]; win[j][1] = win[j][2]; }
    }
}

// ---------------------------------------------------------------------------
// final transpose: t [MTOT][256] f32 -> out [B][256][NTOK] (LDS tiled)
// ---------------------------------------------------------------------------
__global__ __launch_bounds__(256) void tr_out(
    const float* __restrict__ tin, float* __restrict__ outp)
{
    __shared__ float tile[32][33];
    const int m0 = blockIdx.x * 32;
    const int c0 = blockIdx.y * 32;
    const int t = threadIdx.x;
    const int tc = t & 31, tr = t >> 5;
    #pragma unroll
    for (int r = 0; r < 4; ++r)
        tile[tr + r * 8][tc] = tin[(size_t)(m0 + tr + r * 8) * 256 + c0 + tc];
    __syncthreads();
    const int b = (m0 >= NTOK) ? 1 : 0;
    const int n0 = m0 - b * NTOK;
    #pragma unroll
    for (int r = 0; r < 4; ++r)
        outp[((size_t)b * 256 + c0 + tr + r * 8) * NTOK + n0 + tc] = tile[tc][tr + r * 8];
}

// ---------------------------------------------------------------------------
// launch
// ---------------------------------------------------------------------------
extern "C" void kernel_launch(void* const* d_in, const int* in_sizes, int n_in,
                              void* d_out, int out_size, void* d_ws, size_t ws_size,
                              hipStream_t stream)
{
    (void)in_sizes; (void)n_in; (void)out_size; (void)ws_size;
    const float* x     = (const float*)d_in[0];
    const float* Wx_w  = (const float*)d_in[1];
    const float* Wx_b  = (const float*)d_in[2];
    const float* Wq    = (const float*)d_in[3];
    const float* bq    = (const float*)d_in[4];
    const float* Wk    = (const float*)d_in[5];
    const float* bk    = (const float*)d_in[6];
    const float* Wv    = (const float*)d_in[7];
    const float* bv    = (const float*)d_in[8];
    const float* Wo    = (const float*)d_in[9];
    const float* bo    = (const float*)d_in[10];
    const float* ln1_g = (const float*)d_in[11];
    const float* ln1_b = (const float*)d_in[12];
    const float* ln2_g = (const float*)d_in[13];
    const float* ln2_b = (const float*)d_in[14];
    const float* fw1   = (const float*)d_in[15];
    const float* fb1   = (const float*)d_in[16];
    const float* fw2   = (const float*)d_in[17];
    const float* fb2   = (const float*)d_in[18];
    const float* pw    = (const float*)d_in[19];
    const float* pb    = (const float*)d_in[20];
    float* out = (float*)d_out;

    char* p = (char*)d_ws;
    float* tA            = (float*)p;          p += (size_t)MTOT * 256 * 4;
    float* tB            = (float*)p;          p += (size_t)MTOT * 256 * 4;
    unsigned short* tbf  = (unsigned short*)p; p += (size_t)MTOT * 256 * 2;
    unsigned short* qkv  = (unsigned short*)p; p += (size_t)MTOT * 768 * 2;
    unsigned short* hbf  = (unsigned short*)p; p += (size_t)MTOT * 512 * 2;   // also kvT
    unsigned short* ob   = (unsigned short*)p; p += (size_t)MTOT * 256 * 2;
    unsigned short* xbf  = (unsigned short*)p; p += (size_t)MTOT * 128 * 2;
    unsigned short* wqkv_t = (unsigned short*)p; p += (size_t)786432 * 2;
    unsigned short* wo_t   = (unsigned short*)p; p += (size_t)262144 * 2;
    unsigned short* w1_t   = (unsigned short*)p; p += (size_t)524288 * 2;
    unsigned short* w2_t   = (unsigned short*)p; p += (size_t)524288 * 2;
    unsigned short* wx_bf  = (unsigned short*)p; p += (size_t)32768 * 2;
    unsigned short* wp     = (unsigned short*)p; p += (size_t)BATCH * 65536 * 2;
    float* bqkv = (float*)p; p += 3072 * 4;
    float* ctx  = (float*)p; p += 16384 * 4;
    float* Sk   = (float*)p; p += 512 * 4;
    float* ctxp = (float*)p; p += (size_t)NSPLIT * 16384 * 4;
    float* skp  = (float*)p; p += (size_t)NSPLIT * 512 * 4;
    unsigned short* kvT = hbf;   // overlays FFN hidden (disjoint lifetime)

    hipLaunchKernelGGL(conv_weights, dim3(8333), dim3(256), 0, stream,
                       Wq, Wk, Wv, Wo, fw1, fw2, Wx_w, bq, bk, bv,
                       wqkv_t, wo_t, w1_t, w2_t, wx_bf, bqkv);
    hipLaunchKernelGGL(conv_x, dim3(NTOK / 32, CIN / 32, BATCH), dim3(256), 0, stream,
                       x, xbf);

    // input 1x1x1 conv + relu -> tA f32 + tbf bf16  (K=128)
    hipLaunchKernelGGL((gemm_bf16<1, 2, 128, 1>), dim3(216, 2, 1), dim3(256), 0, stream,
                       xbf, CIN, wx_bf, CIN, Wx_b, tA, tbf, 256,
                       (long)0, (long)0, (long)0);

    for (int i = 0; i < NLAYERS; ++i) {
        float* tin  = (i & 1) ? tB : tA;
        float* tout = (i & 1) ? tA : tB;

        // fused QKV: [M,256] x [256,768], 3 M-tiles per block
        hipLaunchKernelGGL((gemm_bf16<0, 1, 256, 3>), dim3(72, 6, 1), dim3(256), 0, stream,
                           tbf, 256, wqkv_t + (size_t)i * 196608, 256,
                           bqkv + i * 768, nullptr, qkv, 768,
                           (long)0, (long)0, (long)0);

        // ctx path: transpose -> MFMA split-K -> reduce (no atomics, no memset)
        hipLaunchKernelGGL(kvt_kernel, dim3(NTOK / 64, NHEAD, BATCH), dim3(256), 0, stream,
                           qkv, kvT);
        hipLaunchKernelGGL(ctx_mfma, dim3(NSPLIT, NHEAD, BATCH), dim3(256), 0, stream,
                           kvT, ctxp, skp);
        hipLaunchKernelGGL(ctxred, dim3(66), dim3(256), 0, stream, ctxp, skp, ctx, Sk);

        // q softmax in place + W' = (ctx/Sk) @ Wo (per batch)
        hipLaunchKernelGGL(qsm_kernel, dim3(3456), dim3(256), 0, stream, qkv);
        hipLaunchKernelGGL(ctxwo_kernel, dim3(NHEAD, BATCH), dim3(256), 0, stream,
                           ctx, Sk, wo_t + (size_t)i * 65536, wp);

        // o_proj = qs @ W' + bo  (batched over z)
        hipLaunchKernelGGL((gemm_bf16<0, 1, 256, 1>), dim3(108, 2, BATCH), dim3(256), 0, stream,
                           qkv, 768, wp, 256, bo + i * 256, nullptr, ob, 256,
                           (long)NTOK * 768, (long)65536, (long)NTOK * 256);

        hipLaunchKernelGGL((ln_kernel<1>), dim3(MTOT), dim3(256), 0, stream,
                           tin, ob, ln1_g + i * 256, ln1_b + i * 256, tbf);

        // FFN (hbf free again: kvT consumed)
        hipLaunchKernelGGL((gemm_bf16<2, 1, 256, 2>), dim3(108, 4, 1), dim3(256), 0, stream,
                           tbf, 256, w1_t + (size_t)i * 131072, 256,
                           fb1 + i * 512, nullptr, hbf, 512,
                           (long)0, (long)0, (long)0);
        hipLaunchKernelGGL((gemm_bf16<0, 1, 512, 1>), dim3(216, 2, 1), dim3(256), 0, stream,
                           hbf, 512, w2_t + (size_t)i * 131072, 512,
                           fb2 + i * 256, nullptr, ob, 256,
                           (long)0, (long)0, (long)0);
        hipLaunchKernelGGL((ln_kernel<0>), dim3(MTOT), dim3(256), 0, stream,
                           tin, ob, ln2_g + i * 256, ln2_b + i * 256, nullptr);

        // depthwise conv + residual -> tout f32 (+ tbf bf16 except last layer)
        if (i < NLAYERS - 1)
            hipLaunchKernelGGL((posconv_kernel<1>), dim3(576, BATCH), dim3(256), 0, stream,
                               tin, pw + (size_t)i * 6912, pb + i * 256, tout, tbf);
        else
            hipLaunchKernelGGL((posconv_kernel<0>), dim3(576, BATCH), dim3(256), 0, stream,
                               tin, pw + (size_t)i * 6912, pb + i * 256, tout, nullptr);
    }

    // layer 3 wrote tA
    hipLaunchKernelGGL(tr_out, dim3(MTOT / 32, 8), dim3(256), 0, stream, tA, out);
}

// Round 5
// 799.998 us; speedup vs baseline: 1.2194x; 1.2194x over previous
//
#include <hip/hip_runtime.h>
#include <math.h>

#define NTOK 13824            // 24*24*24
#define MTOT 27648            // B*NTOK
#define BATCH 2
#define CIN 128
#define DMODEL 256
#define NHEAD 8
#define NLAYERS 4
#define DFF 512
#define NSPLIT 27
#define KVHALF ((size_t)BATCH * 256 * NTOK)

typedef float f32x4 __attribute__((ext_vector_type(4)));
typedef __bf16 bf16x8 __attribute__((ext_vector_type(8)));
typedef __attribute__((address_space(1))) void gvoid;
typedef __attribute__((address_space(3))) void lvoid;

// async global->LDS, 16B per lane. LDS dest must be uniform-base + lane*16.
#define GLDS16(g, l) __builtin_amdgcn_global_load_lds((gvoid*)(g), (lvoid*)(l), 16, 0, 0)

__device__ __forceinline__ unsigned short f2bf(float f) {
    unsigned u = __float_as_uint(f);
    return (unsigned short)((u + 0x7FFFu + ((u >> 16) & 1u)) >> 16);
}
__device__ __forceinline__ float bf2f(unsigned short h) {
    return __uint_as_float(((unsigned)h) << 16);
}

// ---------------------------------------------------------------------------
// bf16 MFMA GEMM: C[M x N] = act(A[M x K](bf16) * B[K x N] + bias)
// B supplied TRANSPOSED: Bt[N][K] bf16. 128x128 tile, BK=64, 256 threads.
// Round-2 proven structure: double-buffered LDS + global_load_lds prefetch,
// STAGE(next) before COMPUTE(cur), one barrier per 64-K-tile; m201 both-sides
// XOR swizzle (0 bank conflicts measured). Added: bijective XCD swizzle on
// (bx,by) (all grids have nwg % 8 == 0).
// ACT: 0 none, 1 relu, 2 gelu(exact),
//      3 = kv-mode: rows are channels (0-255 k -> exp(v+bias[row]),
//          256-511 v -> v+bias[row]), C written to kvT layout
//          [row*NTOK + tok] / [KVHALF + (row-256)*NTOK + tok].
// OUTM: 1 = bf16 C only, 2 = f32 + bf16.
// ---------------------------------------------------------------------------
template<int ACT, int OUTM>
__global__ __launch_bounds__(256) void gemm_bf16(
    const unsigned short* __restrict__ A, int lda,
    const unsigned short* __restrict__ Bt, int ldb,
    const float* __restrict__ bias,
    float* __restrict__ Cf, unsigned short* __restrict__ Cb,
    int ldc, int K, long sA, long sB, long sC)
{
    A  += (size_t)blockIdx.z * sA;
    Bt += (size_t)blockIdx.z * sB;
    if (OUTM == 2) Cf += (size_t)blockIdx.z * sC;
    Cb += (size_t)blockIdx.z * sC;

    // bijective chunked XCD swizzle (requires nwg % 8 == 0)
    int bx, by;
    {
        const int nx  = gridDim.x;
        const int q   = (nx * gridDim.y) >> 3;
        const int lin = blockIdx.y * nx + blockIdx.x;
        const int wg  = (lin & 7) * q + (lin >> 3);
        bx = wg % nx;
        by = wg / nx;
    }

    __shared__ __attribute__((aligned(16))) unsigned short As[2][8192]; // 2 x 128x64
    __shared__ __attribute__((aligned(16))) unsigned short Bs[2][8192]; // 2 x 128x64
    const int t    = threadIdx.x;
    const int lane = t & 63;
    const int wave = t >> 6;
    const int wm = wave & 1, wn = wave >> 1;
    const int m0 = bx * 128, n0 = by * 128;

    // staging map: per pass p (0..3): row = p*32 + (t>>3), 16B chunk = t&7.
    // source k pre-swizzled (involution with the read-side XOR below).
    const int srow = t >> 3;
    const int skid = ((t & 7) * 8) ^ ((srow & 7) << 3);   // shorts within row
    const unsigned short* ga = A  + (size_t)(m0 + srow) * lda + skid;
    const unsigned short* gb = Bt + (size_t)(n0 + srow) * ldb + skid;

    f32x4 acc[4][4];
    #pragma unroll
    for (int i = 0; i < 4; ++i)
        #pragma unroll
        for (int j = 0; j < 4; ++j) acc[i][j] = (f32x4)0.0f;

    const int fm  = lane & 15;
    const int fq8 = (lane >> 4) * 8;
    const int sw3 = (fm & 7) << 3;                 // read-side XOR (shorts)
    const int arow = (wm * 64 + fm) * 64;          // + i*1024
    const int brow = (wn * 64 + fm) * 64;          // + j*1024

#define STAGE(bufi, kk)                                                        \
    {                                                                          \
        _Pragma("unroll")                                                      \
        for (int p = 0; p < 4; ++p) {                                          \
            GLDS16(ga + (size_t)p * 32 * lda + (kk), &As[bufi][p * 2048 + t * 8]); \
            GLDS16(gb + (size_t)p * 32 * ldb + (kk), &Bs[bufi][p * 2048 + t * 8]); \
        }                                                                      \
    }

#define COMPUTE(bufi)                                                          \
    {                                                                          \
        _Pragma("unroll")                                                      \
        for (int ks = 0; ks < 2; ++ks) {                                       \
            bf16x8 af[4], bg[4];                                               \
            const int kidx = (fq8 + ks * 32) ^ sw3;                            \
            _Pragma("unroll")                                                  \
            for (int i = 0; i < 4; ++i)                                        \
                af[i] = *(const bf16x8*)(&As[bufi][arow + i * 1024 + kidx]);   \
            _Pragma("unroll")                                                  \
            for (int j = 0; j < 4; ++j)                                        \
                bg[j] = *(const bf16x8*)(&Bs[bufi][brow + j * 1024 + kidx]);   \
            _Pragma("unroll")                                                  \
            for (int i = 0; i < 4; ++i)                                        \
                _Pragma("unroll")                                              \
                for (int j = 0; j < 4; ++j)                                    \
                    acc[i][j] = __builtin_amdgcn_mfma_f32_16x16x32_bf16(       \
                        af[i], bg[j], acc[i][j], 0, 0, 0);                     \
        }                                                                      \
    }

    STAGE(0, 0)
    __syncthreads();
    const int NT = K >> 6;
    int cur = 0;
    for (int t64 = 0; t64 < NT - 1; ++t64) {
        STAGE(cur ^ 1, (t64 + 1) * 64)    // prefetch next tile (in flight
        COMPUTE(cur)                      //  during this tile's compute)
        __syncthreads();                  // drains vmcnt -> next buf ready
        cur ^= 1;
    }
    COMPUTE(cur)

#undef STAGE
#undef COMPUTE

    if constexpr (ACT == 3) {
        // kv-mode epilogue: row = channel, col = token.
        const int cb  = n0 + wn * 64 + fm;                  // token
        const int rbs = m0 + wm * 64 + (lane >> 4) * 4;     // channel row
        #pragma unroll
        for (int i = 0; i < 4; ++i) {
            #pragma unroll
            for (int r = 0; r < 4; ++r) {
                const int row = rbs + i * 16 + r;
                const float bv = bias[row];
                const size_t base = (row < 256)
                    ? (size_t)row * NTOK
                    : KVHALF + (size_t)(row - 256) * NTOK;
                #pragma unroll
                for (int j = 0; j < 4; ++j) {
                    float v = acc[i][j][r] + bv;
                    if (row < 256) v = __expf(v);
                    Cb[base + cb + j * 16] = f2bf(v);
                }
            }
        }
        return;
    }

    const int cb  = n0 + wn * 64 + fm;
    const int rbs = m0 + wm * 64 + (lane >> 4) * 4;
    #pragma unroll
    for (int j = 0; j < 4; ++j) {
        const int n = cb + j * 16;
        const float bv = bias[n];
        #pragma unroll
        for (int i = 0; i < 4; ++i) {
            #pragma unroll
            for (int r = 0; r < 4; ++r) {
                float v = acc[i][j][r] + bv;
                if (ACT == 1) v = fmaxf(v, 0.0f);
                if (ACT == 2) v = 0.5f * v * (1.0f + erff(v * 0.7071067811865476f));
                const size_t off = (size_t)(rbs + i * 16 + r) * ldc + n;
                if (OUTM == 2) Cf[off] = v;
                Cb[off] = f2bf(v);
            }
        }
    }
}

// ---------------------------------------------------------------------------
// one-shot weight conversion: transpose to [N][K] bf16 + bias concat
// ---------------------------------------------------------------------------
#define CW_QKV  786432   // 4*768*256
#define CW_O   1048576   // + 4*256*256
#define CW_1   1572864   // + 4*512*256
#define CW_2   2097152   // + 4*256*512
#define CW_X   2129920   // + 256*128
#define CW_B   2132992   // + 4*768
__global__ __launch_bounds__(256) void conv_weights(
    const float* __restrict__ Wq, const float* __restrict__ Wk,
    const float* __restrict__ Wv, const float* __restrict__ Wo,
    const float* __restrict__ fw1, const float* __restrict__ fw2,
    const float* __restrict__ Wx_w,
    const float* __restrict__ bq, const float* __restrict__ bk,
    const float* __restrict__ bv,
    unsigned short* __restrict__ wqkv_t, unsigned short* __restrict__ wo_t,
    unsigned short* __restrict__ w1_t, unsigned short* __restrict__ w2_t,
    unsigned short* __restrict__ wx_bf, float* __restrict__ bqkv)
{
    const int e = blockIdx.x * 256 + threadIdx.x;
    if (e < CW_QKV) {
        const int i = e / 196608, r = e % 196608;
        const int n = r / 256, k = r % 256;
        const float* src = (n < 256) ? Wq : (n < 512) ? Wk : Wv;
        wqkv_t[e] = f2bf(src[((size_t)i * 256 + k) * 256 + (n & 255)]);
    } else if (e < CW_O) {
        const int r = e - CW_QKV;
        const int i = r / 65536, rr = r % 65536, n = rr / 256, k = rr % 256;
        wo_t[r] = f2bf(Wo[((size_t)i * 256 + k) * 256 + n]);
    } else if (e < CW_1) {
        const int r = e - CW_O;
        const int i = r / 131072, rr = r % 131072, n = rr / 256, k = rr % 256;
        w1_t[r] = f2bf(fw1[((size_t)i * 256 + k) * 512 + n]);
    } else if (e < CW_2) {
        const int r = e - CW_1;
        const int i = r / 131072, rr = r % 131072, n = rr / 512, k = rr % 512;
        w2_t[r] = f2bf(fw2[((size_t)i * 512 + k) * 256 + n]);
    } else if (e < CW_X) {
        const int r = e - CW_2;
        wx_bf[r] = f2bf(Wx_w[r]);     // Wx_w [out][in] is already B^T layout
    } else if (e < CW_B) {
        const int r = e - CW_X;
        const int i = r / 768, j = r % 768;
        const float v = (j < 256) ? bq[i * 256 + j]
                      : (j < 512) ? bk[i * 256 + j - 256]
                                  : bv[i * 256 + j - 512];
        bqkv[r] = v;
    }
}

// ---------------------------------------------------------------------------
// x [B][CIN][NTOK] f32 -> xbf [(b,n)][CIN] bf16, LDS 32x32 tile transpose.
// ---------------------------------------------------------------------------
__global__ __launch_bounds__(256) void conv_x(
    const float* __restrict__ x, unsigned short* __restrict__ xbf)
{
    __shared__ float tile[32][33];
    const int n0 = blockIdx.x * 32;
    const int c0 = blockIdx.y * 32;
    const int b  = blockIdx.z;
    const int t = threadIdx.x;
    const int tn = t & 31, tc = t >> 5;
    #pragma unroll
    for (int p = 0; p < 4; ++p)
        tile[tc + p * 8][tn] =
            x[((size_t)(b * CIN + c0 + tc + p * 8)) * NTOK + n0 + tn];
    __syncthreads();
    const int cc = t & 31, nr = t >> 5;
    #pragma unroll
    for (int p = 0; p < 4; ++p)
        xbf[((size_t)(b * NTOK + n0 + nr + p * 8)) * CIN + c0 + cc] =
            f2bf(tile[cc][nr + p * 8]);
}

// ---------------------------------------------------------------------------
// q softmax over dk=32, in place on qbuf [M][256]. 8 bf16 per lane.
// ---------------------------------------------------------------------------
__global__ __launch_bounds__(256) void qsm_kernel(unsigned short* __restrict__ qbuf)
{
    const int g = blockIdx.x * 256 + threadIdx.x;   // < MTOT*32
    const int row = g >> 5;
    const int cg  = g & 31;                          // 8-channel chunk
    unsigned short* p = qbuf + (size_t)row * 256 + cg * 8;
    uint4 raw = *(const uint4*)p;
    unsigned short* rp = (unsigned short*)&raw;
    float v[8];
    #pragma unroll
    for (int j = 0; j < 8; ++j) v[j] = bf2f(rp[j]);
    float m = v[0];
    #pragma unroll
    for (int j = 1; j < 8; ++j) m = fmaxf(m, v[j]);
    m = fmaxf(m, __shfl_xor(m, 1, 64));
    m = fmaxf(m, __shfl_xor(m, 2, 64));
    float s = 0.0f;
    #pragma unroll
    for (int j = 0; j < 8; ++j) { v[j] = __expf(v[j] - m); s += v[j]; }
    s += __shfl_xor(s, 1, 64);
    s += __shfl_xor(s, 2, 64);
    const float r = 1.0f / s;
    #pragma unroll
    for (int j = 0; j < 8; ++j) rp[j] = f2bf(v[j] * r);
    *(uint4*)p = raw;
}

// ---------------------------------------------------------------------------
// ctx via MFMA, split-K, NO atomics.
// grid (NSPLIT, NHEAD, B), block 256 (4 waves). Each wave: 128 tokens,
// 16x16x32 MFMA, A = expkT rows (d), B = vT rows (e) -- direct global
// bf16x8 fragment loads (contiguous). Sk partials from A-frag sums.
// ---------------------------------------------------------------------------
__global__ __launch_bounds__(256) void ctx_mfma(
    const unsigned short* __restrict__ kvT,
    float* __restrict__ ctxp, float* __restrict__ skp)
{
    const int s = blockIdx.x, h = blockIdx.y, b = blockIdx.z;
    const int t = threadIdx.x, w = t >> 6, l = t & 63;
    const int fm = l & 15, fq = (l >> 4) * 8;
    const size_t rowA = (size_t)(b * 256 + h * 32 + fm) * NTOK;
    const int n0 = s * 512 + w * 128 + fq;
    const unsigned short* pa = kvT + rowA + n0;
    const unsigned short* pb = kvT + KVHALF + rowA + n0;

    f32x4 acc[2][2];
    #pragma unroll
    for (int x = 0; x < 2; ++x)
        #pragma unroll
        for (int y = 0; y < 2; ++y) acc[x][y] = (f32x4)0.0f;
    float ss0 = 0.0f, ss1 = 0.0f;

    #pragma unroll
    for (int step = 0; step < 4; ++step) {
        const int ko = step * 32;
        const uint4 ra0 = *(const uint4*)(pa + ko);
        const uint4 ra1 = *(const uint4*)(pa + (size_t)16 * NTOK + ko);
        const uint4 rb0 = *(const uint4*)(pb + ko);
        const uint4 rb1 = *(const uint4*)(pb + (size_t)16 * NTOK + ko);
        const bf16x8 a0 = *(const bf16x8*)&ra0;
        const bf16x8 a1 = *(const bf16x8*)&ra1;
        const bf16x8 b0 = *(const bf16x8*)&rb0;
        const bf16x8 b1 = *(const bf16x8*)&rb1;
        acc[0][0] = __builtin_amdgcn_mfma_f32_16x16x32_bf16(a0, b0, acc[0][0], 0, 0, 0);
        acc[0][1] = __builtin_amdgcn_mfma_f32_16x16x32_bf16(a0, b1, acc[0][1], 0, 0, 0);
        acc[1][0] = __builtin_amdgcn_mfma_f32_16x16x32_bf16(a1, b0, acc[1][0], 0, 0, 0);
        acc[1][1] = __builtin_amdgcn_mfma_f32_16x16x32_bf16(a1, b1, acc[1][1], 0, 0, 0);
        const unsigned short* u0 = (const unsigned short*)&ra0;
        const unsigned short* u1 = (const unsigned short*)&ra1;
        #pragma unroll
        for (int j = 0; j < 8; ++j) { ss0 += bf2f(u0[j]); ss1 += bf2f(u1[j]); }
    }

    ss0 += __shfl_xor(ss0, 16, 64); ss0 += __shfl_xor(ss0, 32, 64);
    ss1 += __shfl_xor(ss1, 16, 64); ss1 += __shfl_xor(ss1, 32, 64);
    __shared__ float skw[4][32];
    __shared__ float redc[4][32][33];
    if (l < 16) { skw[w][fm] = ss0; skw[w][16 + fm] = ss1; }

    const int rb4 = (l >> 4) * 4;
    #pragma unroll
    for (int x = 0; x < 2; ++x)
        #pragma unroll
        for (int y = 0; y < 2; ++y)
            #pragma unroll
            for (int r = 0; r < 4; ++r)
                redc[w][x * 16 + rb4 + r][y * 16 + fm] = acc[x][y][r];
    __syncthreads();

    if (t < 32)
        skp[(size_t)s * 512 + b * 256 + h * 32 + t] =
            skw[0][t] + skw[1][t] + skw[2][t] + skw[3][t];

    const int e0 = t * 4;
    const int dd = e0 >> 5, c0 = e0 & 31;
    float4 o;
    o.x = redc[0][dd][c0+0] + redc[1][dd][c0+0] + redc[2][dd][c0+0] + redc[3][dd][c0+0];
    o.y = redc[0][dd][c0+1] + redc[1][dd][c0+1] + redc[2][dd][c0+1] + redc[3][dd][c0+1];
    o.z = redc[0][dd][c0+2] + redc[1][dd][c0+2] + redc[2][dd][c0+2] + redc[3][dd][c0+2];
    o.w = redc[0][dd][c0+3] + redc[1][dd][c0+3] + redc[2][dd][c0+3] + redc[3][dd][c0+3];
    *(float4*)(ctxp + ((size_t)s * 16 + b * 8 + h) * 1024 + e0) = o;
}

// reduce split-K partials: ctx[16][1024] and Sk[512]. grid 66 x 256.
__global__ __launch_bounds__(256) void ctxred(
    const float* __restrict__ ctxp, const float* __restrict__ skp,
    float* __restrict__ ctx, float* __restrict__ Sk)
{
    const int o = blockIdx.x * 256 + threadIdx.x;   // 0..16895
    if (o < 16384) {
        float a = 0.0f;
        for (int s = 0; s < NSPLIT; ++s) a += ctxp[(size_t)s * 16384 + o];
        ctx[o] = a;
    } else {
        const int c = o - 16384;
        float a = 0.0f;
        for (int s = 0; s < NSPLIT; ++s) a += skp[(size_t)s * 512 + c];
        Sk[c] = a;
    }
}

// ---------------------------------------------------------------------------
// W'[b][n][h*32+d] = (1/sqrt(dk)) * (1/Sk[d]) * sum_e ctx[b][h][d][e] * Wo[h*32+e][n]
// ---------------------------------------------------------------------------
__global__ __launch_bounds__(256) void ctxwo_kernel(
    const float* __restrict__ ctx, const float* __restrict__ Sk,
    const unsigned short* __restrict__ wo_t, unsigned short* __restrict__ wp)
{
    const int h = blockIdx.x, b = blockIdx.y;
    const int n = threadIdx.x;
    __shared__ float cl[1024];
    __shared__ float sdk[32];
    {
        const float* cp = ctx + (size_t)(b * 8 + h) * 1024;
        *(float4*)&cl[n * 4] = *(const float4*)&cp[n * 4];
    }
    if (n < 32) sdk[n] = 0.17677669529663687f / Sk[b * 256 + h * 32 + n];
    __syncthreads();
    float w[32];
    const unsigned short* wop = wo_t + (size_t)n * 256 + h * 32;
    #pragma unroll
    for (int e = 0; e < 32; ++e) w[e] = bf2f(wop[e]);
    unsigned short outv[32];
    #pragma unroll
    for (int d = 0; d < 32; ++d) {
        float acc = 0.0f;
        #pragma unroll
        for (int e = 0; e < 32; ++e) acc += cl[d * 32 + e] * w[e];
        outv[d] = f2bf(acc * sdk[d]);
    }
    unsigned short* op = wp + (size_t)b * 65536 + (size_t)n * 256 + h * 32;
    #pragma unroll
    for (int d = 0; d < 32; d += 8)
        *(uint4*)(op + d) = *(uint4*)(outv + d);
}

// ---------------------------------------------------------------------------
// Vectorized LayerNorm: t = LN(t + add(bf16)) * g + b. 8 rows per block,
// one row per 32-lane group, 8 channels per lane (float4 x2 / short8 loads).
// No LDS, no barriers. WB: also write bf16 copy.
// ---------------------------------------------------------------------------
template<int WB>
__global__ __launch_bounds__(256) void ln8_kernel(
    float* __restrict__ t, const unsigned short* __restrict__ add,
    const float* __restrict__ g, const float* __restrict__ bta,
    unsigned short* __restrict__ tbf)
{
    const int l  = threadIdx.x & 31;
    const int rg = threadIdx.x >> 5;
    const size_t row = (size_t)blockIdx.x * 8 + rg;
    const size_t off = row * 256 + l * 8;

    const float4 a0 = *(const float4*)(t + off);
    const float4 a1 = *(const float4*)(t + off + 4);
    const uint4  ad = *(const uint4*)(add + off);
    const unsigned short* ap = (const unsigned short*)&ad;

    float v[8] = {a0.x, a0.y, a0.z, a0.w, a1.x, a1.y, a1.z, a1.w};
    float s = 0.0f;
    #pragma unroll
    for (int k = 0; k < 8; ++k) { v[k] += bf2f(ap[k]); s += v[k]; }
    #pragma unroll
    for (int o = 16; o; o >>= 1) s += __shfl_xor(s, o, 32);
    const float mu = s * (1.0f / 256.0f);

    float s2 = 0.0f;
    #pragma unroll
    for (int k = 0; k < 8; ++k) { v[k] -= mu; s2 += v[k] * v[k]; }
    #pragma unroll
    for (int o = 16; o; o >>= 1) s2 += __shfl_xor(s2, o, 32);
    const float rs = rsqrtf(s2 * (1.0f / 256.0f) + 1e-6f);

    const float4 g0 = *(const float4*)(g + l * 8);
    const float4 g1 = *(const float4*)(g + l * 8 + 4);
    const float4 b0 = *(const float4*)(bta + l * 8);
    const float4 b1 = *(const float4*)(bta + l * 8 + 4);
    const float gg[8] = {g0.x, g0.y, g0.z, g0.w, g1.x, g1.y, g1.z, g1.w};
    const float bb[8] = {b0.x, b0.y, b0.z, b0.w, b1.x, b1.y, b1.z, b1.w};

    float o8[8];
    #pragma unroll
    for (int k = 0; k < 8; ++k) o8[k] = v[k] * rs * gg[k] + bb[k];

    *(float4*)(t + off)     = make_float4(o8[0], o8[1], o8[2], o8[3]);
    *(float4*)(t + off + 4) = make_float4(o8[4], o8[5], o8[6], o8[7]);
    if (WB) {
        uint4 ob_;
        unsigned short* op = (unsigned short*)&ob_;
        #pragma unroll
        for (int k = 0; k < 8; ++k) op[k] = f2bf(o8[k]);
        *(uint4*)(tbf + off) = ob_;
    }
}

// ---------------------------------------------------------------------------
// depthwise 3x3x3 conv + residual, register-resident weights + sliding window.
// WB: 0 f32 out only, 1 f32 + bf16 copy, 2 = TRANSPOSED f32 out
//     (outp treated as [B][256][NTOK]; fuses the final tr_out).
// ---------------------------------------------------------------------------
template<int WB>
__global__ __launch_bounds__(256) void posconv_kernel(
    const float* __restrict__ tin, const float* __restrict__ pw,
    const float* __restrict__ pb, float* __restrict__ outp,
    unsigned short* __restrict__ tbfp)
{
    const int hw = blockIdx.x;            // 0..575
    const int b  = blockIdx.y;
    const int hh = hw / 24, ww = hw % 24;
    const int c  = threadIdx.x;

    float w[27];
    #pragma unroll
    for (int k = 0; k < 27; ++k) w[k] = pw[c * 27 + k];
    const float bias = pb[c];

    const float* base = tin + (size_t)b * NTOK * 256 + c;

    const float* colp[9];
    bool colok[9];
    #pragma unroll
    for (int dh = -1; dh <= 1; ++dh)
        #pragma unroll
        for (int dw = -1; dw <= 1; ++dw) {
            const int j = (dh + 1) * 3 + (dw + 1);
            const int h2 = hh + dh, w2 = ww + dw;
            colok[j] = ((unsigned)h2 < 24u) & ((unsigned)w2 < 24u);
            colp[j] = base + (size_t)((h2 * 24 + w2) * 24) * 256;
        }

    float win[9][3];
    #pragma unroll
    for (int j = 0; j < 9; ++j) {
        win[j][0] = 0.0f;
        win[j][1] = colok[j] ? colp[j][0] : 0.0f;
    }

    if constexpr (WB == 2) {
        float o24[24];
        #pragma unroll
        for (int d = 0; d < 24; ++d) {
            #pragma unroll
            for (int j = 0; j < 9; ++j)
                win[j][2] = (colok[j] && d < 23) ? colp[j][(d + 1) * 256] : 0.0f;
            float acc = bias + win[4][1];
            #pragma unroll
            for (int j = 0; j < 9; ++j) {
                acc += w[j * 3 + 0] * win[j][0];
                acc += w[j * 3 + 1] * win[j][1];
                acc += w[j * 3 + 2] * win[j][2];
            }
            o24[d] = acc;
            #pragma unroll
            for (int j = 0; j < 9; ++j) { win[j][0] = win[j][1]; win[j][1] = win[j][2]; }
        }
        float* op = outp + ((size_t)b * 256 + c) * NTOK + hw * 24;
        #pragma unroll
        for (int q = 0; q < 6; ++q)
            *(float4*)(op + q * 4) =
                make_float4(o24[q*4], o24[q*4+1], o24[q*4+2], o24[q*4+3]);
        return;
    }

    float* ob = outp + ((size_t)b * NTOK + (size_t)hw * 24) * 256 + c;
    unsigned short* tb = (WB == 1)
        ? (tbfp + ((size_t)b * NTOK + (size_t)hw * 24) * 256 + c)
        : (unsigned short*)nullptr;

    for (int d = 0; d < 24; ++d) {
        #pragma unroll
        for (int j = 0; j < 9; ++j)
            win[j][2] = (colok[j] && d < 23) ? colp[j][(d + 1) * 256] : 0.0f;

        float acc = bias + win[4][1];
        #pragma unroll
        for (int j = 0; j < 9; ++j) {
            acc += w[j * 3 + 0] * win[j][0];
            acc += w[j * 3 + 1] * win[j][1];
            acc += w[j * 3 + 2] * win[j][2];
        }
        ob[d * 256] = acc;
        if (WB == 1) tb[d * 256] = f2bf(acc);

        #pragma unroll
        for (int j = 0; j < 9; ++j) { win[j][0] = win[j][1]; win[j][1] = win[j][2]; }
    }
}

// ---------------------------------------------------------------------------
// launch
// ---------------------------------------------------------------------------
extern "C" void kernel_launch(void* const* d_in, const int* in_sizes, int n_in,
                              void* d_out, int out_size, void* d_ws, size_t ws_size,
                              hipStream_t stream)
{
    (void)in_sizes; (void)n_in; (void)out_size; (void)ws_size;
    const float* x     = (const float*)d_in[0];
    const float* Wx_w  = (const float*)d_in[1];
    const float* Wx_b  = (const float*)d_in[2];
    const float* Wq    = (const float*)d_in[3];
    const float* bq    = (const float*)d_in[4];
    const float* Wk    = (const float*)d_in[5];
    const float* bk    = (const float*)d_in[6];
    const float* Wv    = (const float*)d_in[7];
    const float* bv    = (const float*)d_in[8];
    const float* Wo    = (const float*)d_in[9];
    const float* bo    = (const float*)d_in[10];
    const float* ln1_g = (const float*)d_in[11];
    const float* ln1_b = (const float*)d_in[12];
    const float* ln2_g = (const float*)d_in[13];
    const float* ln2_b = (const float*)d_in[14];
    const float* fw1   = (const float*)d_in[15];
    const float* fb1   = (const float*)d_in[16];
    const float* fw2   = (const float*)d_in[17];
    const float* fb2   = (const float*)d_in[18];
    const float* pw    = (const float*)d_in[19];
    const float* pb    = (const float*)d_in[20];
    float* out = (float*)d_out;

    char* p = (char*)d_ws;
    float* tA            = (float*)p;          p += (size_t)MTOT * 256 * 4;
    float* tB            = (float*)p;          p += (size_t)MTOT * 256 * 4;
    unsigned short* tbf  = (unsigned short*)p; p += (size_t)MTOT * 256 * 2;
    unsigned short* qbuf = (unsigned short*)p; p += (size_t)MTOT * 256 * 2;
    unsigned short* hbf  = (unsigned short*)p; p += (size_t)MTOT * 512 * 2;   // also kvT
    unsigned short* ob   = (unsigned short*)p; p += (size_t)MTOT * 256 * 2;
    unsigned short* xbf  = (unsigned short*)p; p += (size_t)MTOT * 128 * 2;
    unsigned short* wqkv_t = (unsigned short*)p; p += (size_t)786432 * 2;
    unsigned short* wo_t   = (unsigned short*)p; p += (size_t)262144 * 2;
    unsigned short* w1_t   = (unsigned short*)p; p += (size_t)524288 * 2;
    unsigned short* w2_t   = (unsigned short*)p; p += (size_t)524288 * 2;
    unsigned short* wx_bf  = (unsigned short*)p; p += (size_t)32768 * 2;
    unsigned short* wp     = (unsigned short*)p; p += (size_t)BATCH * 65536 * 2;
    float* bqkv = (float*)p; p += 3072 * 4;
    float* ctx  = (float*)p; p += 16384 * 4;
    float* Sk   = (float*)p; p += 512 * 4;
    float* ctxp = (float*)p; p += (size_t)NSPLIT * 16384 * 4;
    float* skp  = (float*)p; p += (size_t)NSPLIT * 512 * 4;
    unsigned short* kvT = hbf;   // overlays FFN hidden (disjoint lifetime)

    hipLaunchKernelGGL(conv_weights, dim3(8333), dim3(256), 0, stream,
                       Wq, Wk, Wv, Wo, fw1, fw2, Wx_w, bq, bk, bv,
                       wqkv_t, wo_t, w1_t, w2_t, wx_bf, bqkv);
    hipLaunchKernelGGL(conv_x, dim3(NTOK / 32, CIN / 32, BATCH), dim3(256), 0, stream,
                       x, xbf);

    // input 1x1x1 conv + relu -> tA f32 + tbf bf16
    hipLaunchKernelGGL((gemm_bf16<1, 2>), dim3(216, 2, 1), dim3(256), 0, stream,
                       xbf, CIN, wx_bf, CIN, Wx_b, tA, tbf, 256, CIN,
                       (long)0, (long)0, (long)0);

    for (int i = 0; i < NLAYERS; ++i) {
        float* tin  = (i & 1) ? tB : tA;
        float* tout = (i & 1) ? tA : tB;

        // q projection: [M,256] x [256,256] -> qbuf
        hipLaunchKernelGGL((gemm_bf16<0, 1>), dim3(216, 2, 1), dim3(256), 0, stream,
                           tbf, 256, wqkv_t + (size_t)i * 196608, 256,
                           bqkv + i * 768, nullptr, qbuf, 256, 256,
                           (long)0, (long)0, (long)0);

        // k/v projection TRANSPOSED: A = W_kv [512][256], B = tbf [tok][256]
        // -> C[ch][tok] = exp(k)+bias / v+bias written straight into kvT.
        // (replaces the old kvt transpose kernel entirely)
        hipLaunchKernelGGL((gemm_bf16<3, 1>), dim3(4, 108, BATCH), dim3(256), 0, stream,
                           wqkv_t + (size_t)i * 196608 + 65536, 256,
                           tbf, 256, bqkv + i * 768 + 256,
                           nullptr, kvT, 0, 256,
                           (long)0, (long)NTOK * 256, (long)256 * NTOK);

        // ctx path: MFMA split-K -> reduce (no atomics, no memset)
        hipLaunchKernelGGL(ctx_mfma, dim3(NSPLIT, NHEAD, BATCH), dim3(256), 0, stream,
                           kvT, ctxp, skp);
        hipLaunchKernelGGL(ctxred, dim3(66), dim3(256), 0, stream, ctxp, skp, ctx, Sk);

        // q softmax in place + W' = (ctx/Sk) @ Wo (per batch)
        hipLaunchKernelGGL(qsm_kernel, dim3(3456), dim3(256), 0, stream, qbuf);
        hipLaunchKernelGGL(ctxwo_kernel, dim3(NHEAD, BATCH), dim3(256), 0, stream,
                           ctx, Sk, wo_t + (size_t)i * 65536, wp);

        // o_proj = qs @ W' + bo  (batched over z)
        hipLaunchKernelGGL((gemm_bf16<0, 1>), dim3(108, 2, BATCH), dim3(256), 0, stream,
                           qbuf, 256, wp, 256, bo + i * 256, nullptr, ob, 256, 256,
                           (long)NTOK * 256, (long)65536, (long)NTOK * 256);

        hipLaunchKernelGGL((ln8_kernel<1>), dim3(MTOT / 8), dim3(256), 0, stream,
                           tin, ob, ln1_g + i * 256, ln1_b + i * 256, tbf);

        // FFN (hbf free again: kvT consumed)
        hipLaunchKernelGGL((gemm_bf16<2, 1>), dim3(216, 4, 1), dim3(256), 0, stream,
                           tbf, 256, w1_t + (size_t)i * 131072, 256,
                           fb1 + i * 512, nullptr, hbf, 512, 256,
                           (long)0, (long)0, (long)0);
        hipLaunchKernelGGL((gemm_bf16<0, 1>), dim3(216, 2, 1), dim3(256), 0, stream,
                           hbf, 512, w2_t + (size_t)i * 131072, 512,
                           fb2 + i * 256, nullptr, ob, 256, 512,
                           (long)0, (long)0, (long)0);
        hipLaunchKernelGGL((ln8_kernel<0>), dim3(MTOT / 8), dim3(256), 0, stream,
                           tin, ob, ln2_g + i * 256, ln2_b + i * 256, nullptr);

        // depthwise conv + residual; last layer writes transposed into `out`
        if (i < NLAYERS - 1)
            hipLaunchKernelGGL((posconv_kernel<1>), dim3(576, BATCH), dim3(256), 0, stream,
                               tin, pw + (size_t)i * 6912, pb + i * 256, tout, tbf);
        else
            hipLaunchKernelGGL((posconv_kernel<2>), dim3(576, BATCH), dim3(256), 0, stream,
                               tin, pw + (size_t)i * 6912, pb + i * 256, out, nullptr);
    }
}

// Round 6
// 788.505 us; speedup vs baseline: 1.2371x; 1.0146x over previous
//
#include <hip/hip_runtime.h>
#include <math.h>

#define NTOK 13824            // 24*24*24
#define MTOT 27648            // B*NTOK
#define BATCH 2
#define CIN 128
#define DMODEL 256
#define NHEAD 8
#define NLAYERS 4
#define DFF 512
#define NSPLIT 27
#define KVHALF ((size_t)BATCH * 256 * NTOK)

typedef float f32x4 __attribute__((ext_vector_type(4)));
typedef __bf16 bf16x8 __attribute__((ext_vector_type(8)));
typedef __attribute__((address_space(1))) void gvoid;
typedef __attribute__((address_space(3))) void lvoid;

// async global->LDS, 16B per lane. LDS dest must be uniform-base + lane*16.
#define GLDS16(g, l) __builtin_amdgcn_global_load_lds((gvoid*)(g), (lvoid*)(l), 16, 0, 0)

__device__ __forceinline__ unsigned short f2bf(float f) {
    unsigned u = __float_as_uint(f);
    return (unsigned short)((u + 0x7FFFu + ((u >> 16) & 1u)) >> 16);
}
__device__ __forceinline__ float bf2f(unsigned short h) {
    return __uint_as_float(((unsigned)h) << 16);
}

// ---------------------------------------------------------------------------
// bf16 MFMA GEMM: C[M x N] = act(A[M x K](bf16) * B[K x N] + bias)
// B supplied TRANSPOSED: Bt[N][K] bf16. 128x128 tile, BK=64, 256 threads.
// Round-2 proven structure: double-buffered LDS + global_load_lds prefetch,
// STAGE(next) before COMPUTE(cur), one barrier per 64-K-tile; m201 both-sides
// XOR swizzle (0 bank conflicts measured). Bijective XCD swizzle on (bx,by).
// ACT: 0 none, 1 relu, 2 gelu(exact),
//      3 = kv-mode: rows are channels (0-255 k -> exp(v+bias[row]),
//          256-511 v -> v+bias[row]), C written to kvT layout.
// OUTM: 1 = bf16 C only, 2 = f32 + bf16.
// ---------------------------------------------------------------------------
template<int ACT, int OUTM>
__global__ __launch_bounds__(256) void gemm_bf16(
    const unsigned short* __restrict__ A, int lda,
    const unsigned short* __restrict__ Bt, int ldb,
    const float* __restrict__ bias,
    float* __restrict__ Cf, unsigned short* __restrict__ Cb,
    int ldc, int K, long sA, long sB, long sC)
{
    A  += (size_t)blockIdx.z * sA;
    Bt += (size_t)blockIdx.z * sB;
    if (OUTM == 2) Cf += (size_t)blockIdx.z * sC;
    Cb += (size_t)blockIdx.z * sC;

    // bijective chunked XCD swizzle (requires nwg % 8 == 0)
    int bx, by;
    {
        const int nx  = gridDim.x;
        const int q   = (nx * gridDim.y) >> 3;
        const int lin = blockIdx.y * nx + blockIdx.x;
        const int wg  = (lin & 7) * q + (lin >> 3);
        bx = wg % nx;
        by = wg / nx;
    }

    __shared__ __attribute__((aligned(16))) unsigned short As[2][8192]; // 2 x 128x64
    __shared__ __attribute__((aligned(16))) unsigned short Bs[2][8192]; // 2 x 128x64
    const int t    = threadIdx.x;
    const int lane = t & 63;
    const int wave = t >> 6;
    const int wm = wave & 1, wn = wave >> 1;
    const int m0 = bx * 128, n0 = by * 128;

    // staging map: per pass p (0..3): row = p*32 + (t>>3), 16B chunk = t&7.
    // source k pre-swizzled (involution with the read-side XOR below).
    const int srow = t >> 3;
    const int skid = ((t & 7) * 8) ^ ((srow & 7) << 3);   // shorts within row
    const unsigned short* ga = A  + (size_t)(m0 + srow) * lda + skid;
    const unsigned short* gb = Bt + (size_t)(n0 + srow) * ldb + skid;

    f32x4 acc[4][4];
    #pragma unroll
    for (int i = 0; i < 4; ++i)
        #pragma unroll
        for (int j = 0; j < 4; ++j) acc[i][j] = (f32x4)0.0f;

    const int fm  = lane & 15;
    const int fq8 = (lane >> 4) * 8;
    const int sw3 = (fm & 7) << 3;                 // read-side XOR (shorts)
    const int arow = (wm * 64 + fm) * 64;          // + i*1024
    const int brow = (wn * 64 + fm) * 64;          // + j*1024

#define STAGE(bufi, kk)                                                        \
    {                                                                          \
        _Pragma("unroll")                                                      \
        for (int p = 0; p < 4; ++p) {                                          \
            GLDS16(ga + (size_t)p * 32 * lda + (kk), &As[bufi][p * 2048 + t * 8]); \
            GLDS16(gb + (size_t)p * 32 * ldb + (kk), &Bs[bufi][p * 2048 + t * 8]); \
        }                                                                      \
    }

#define COMPUTE(bufi)                                                          \
    {                                                                          \
        _Pragma("unroll")                                                      \
        for (int ks = 0; ks < 2; ++ks) {                                       \
            bf16x8 af[4], bg[4];                                               \
            const int kidx = (fq8 + ks * 32) ^ sw3;                            \
            _Pragma("unroll")                                                  \
            for (int i = 0; i < 4; ++i)                                        \
                af[i] = *(const bf16x8*)(&As[bufi][arow + i * 1024 + kidx]);   \
            _Pragma("unroll")                                                  \
            for (int j = 0; j < 4; ++j)                                        \
                bg[j] = *(const bf16x8*)(&Bs[bufi][brow + j * 1024 + kidx]);   \
            _Pragma("unroll")                                                  \
            for (int i = 0; i < 4; ++i)                                        \
                _Pragma("unroll")                                              \
                for (int j = 0; j < 4; ++j)                                    \
                    acc[i][j] = __builtin_amdgcn_mfma_f32_16x16x32_bf16(       \
                        af[i], bg[j], acc[i][j], 0, 0, 0);                     \
        }                                                                      \
    }

    STAGE(0, 0)
    __syncthreads();
    const int NT = K >> 6;
    int cur = 0;
    for (int t64 = 0; t64 < NT - 1; ++t64) {
        STAGE(cur ^ 1, (t64 + 1) * 64)    // prefetch next tile (in flight
        COMPUTE(cur)                      //  during this tile's compute)
        __syncthreads();                  // drains vmcnt -> next buf ready
        cur ^= 1;
    }
    COMPUTE(cur)

#undef STAGE
#undef COMPUTE

    if constexpr (ACT == 3) {
        // kv-mode epilogue: row = channel, col = token.
        const int cb  = n0 + wn * 64 + fm;                  // token
        const int rbs = m0 + wm * 64 + (lane >> 4) * 4;     // channel row
        #pragma unroll
        for (int i = 0; i < 4; ++i) {
            #pragma unroll
            for (int r = 0; r < 4; ++r) {
                const int row = rbs + i * 16 + r;
                const float bv = bias[row];
                const size_t base = (row < 256)
                    ? (size_t)row * NTOK
                    : KVHALF + (size_t)(row - 256) * NTOK;
                #pragma unroll
                for (int j = 0; j < 4; ++j) {
                    float v = acc[i][j][r] + bv;
                    if (row < 256) v = __expf(v);
                    Cb[base + cb + j * 16] = f2bf(v);
                }
            }
        }
        return;
    }

    const int cb  = n0 + wn * 64 + fm;
    const int rbs = m0 + wm * 64 + (lane >> 4) * 4;
    #pragma unroll
    for (int j = 0; j < 4; ++j) {
        const int n = cb + j * 16;
        const float bv = bias[n];
        #pragma unroll
        for (int i = 0; i < 4; ++i) {
            #pragma unroll
            for (int r = 0; r < 4; ++r) {
                float v = acc[i][j][r] + bv;
                if (ACT == 1) v = fmaxf(v, 0.0f);
                if (ACT == 2) v = 0.5f * v * (1.0f + erff(v * 0.7071067811865476f));
                const size_t off = (size_t)(rbs + i * 16 + r) * ldc + n;
                if (OUTM == 2) Cf[off] = v;
                Cb[off] = f2bf(v);
            }
        }
    }
}

// ---------------------------------------------------------------------------
// one-shot weight conversion: transpose to [N][K] bf16 + bias concat
// ---------------------------------------------------------------------------
#define CW_QKV  786432   // 4*768*256
#define CW_O   1048576   // + 4*256*256
#define CW_1   1572864   // + 4*512*256
#define CW_2   2097152   // + 4*256*512
#define CW_X   2129920   // + 256*128
#define CW_B   2132992   // + 4*768
__global__ __launch_bounds__(256) void conv_weights(
    const float* __restrict__ Wq, const float* __restrict__ Wk,
    const float* __restrict__ Wv, const float* __restrict__ Wo,
    const float* __restrict__ fw1, const float* __restrict__ fw2,
    const float* __restrict__ Wx_w,
    const float* __restrict__ bq, const float* __restrict__ bk,
    const float* __restrict__ bv,
    unsigned short* __restrict__ wqkv_t, unsigned short* __restrict__ wo_t,
    unsigned short* __restrict__ w1_t, unsigned short* __restrict__ w2_t,
    unsigned short* __restrict__ wx_bf, float* __restrict__ bqkv)
{
    const int e = blockIdx.x * 256 + threadIdx.x;
    if (e < CW_QKV) {
        const int i = e / 196608, r = e % 196608;
        const int n = r / 256, k = r % 256;
        const float* src = (n < 256) ? Wq : (n < 512) ? Wk : Wv;
        wqkv_t[e] = f2bf(src[((size_t)i * 256 + k) * 256 + (n & 255)]);
    } else if (e < CW_O) {
        const int r = e - CW_QKV;
        const int i = r / 65536, rr = r % 65536, n = rr / 256, k = rr % 256;
        wo_t[r] = f2bf(Wo[((size_t)i * 256 + k) * 256 + n]);
    } else if (e < CW_1) {
        const int r = e - CW_O;
        const int i = r / 131072, rr = r % 131072, n = rr / 256, k = rr % 256;
        w1_t[r] = f2bf(fw1[((size_t)i * 256 + k) * 512 + n]);
    } else if (e < CW_2) {
        const int r = e - CW_1;
        const int i = r / 131072, rr = r % 131072, n = rr / 512, k = rr % 512;
        w2_t[r] = f2bf(fw2[((size_t)i * 512 + k) * 256 + n]);
    } else if (e < CW_X) {
        const int r = e - CW_2;
        wx_bf[r] = f2bf(Wx_w[r]);     // Wx_w [out][in] is already B^T layout
    } else if (e < CW_B) {
        const int r = e - CW_X;
        const int i = r / 768, j = r % 768;
        const float v = (j < 256) ? bq[i * 256 + j]
                      : (j < 512) ? bk[i * 256 + j - 256]
                                  : bv[i * 256 + j - 512];
        bqkv[r] = v;
    }
}

// ---------------------------------------------------------------------------
// x [B][CIN][NTOK] f32 -> xbf [(b,n)][CIN] bf16, LDS 32x32 tile transpose.
// ---------------------------------------------------------------------------
__global__ __launch_bounds__(256) void conv_x(
    const float* __restrict__ x, unsigned short* __restrict__ xbf)
{
    __shared__ float tile[32][33];
    const int n0 = blockIdx.x * 32;
    const int c0 = blockIdx.y * 32;
    const int b  = blockIdx.z;
    const int t = threadIdx.x;
    const int tn = t & 31, tc = t >> 5;
    #pragma unroll
    for (int p = 0; p < 4; ++p)
        tile[tc + p * 8][tn] =
            x[((size_t)(b * CIN + c0 + tc + p * 8)) * NTOK + n0 + tn];
    __syncthreads();
    const int cc = t & 31, nr = t >> 5;
    #pragma unroll
    for (int p = 0; p < 4; ++p)
        xbf[((size_t)(b * NTOK + n0 + nr + p * 8)) * CIN + c0 + cc] =
            f2bf(tile[cc][nr + p * 8]);
}

// ---------------------------------------------------------------------------
// q softmax over dk=32, in place on qbuf [M][256]. 8 bf16 per lane.
// ---------------------------------------------------------------------------
__global__ __launch_bounds__(256) void qsm_kernel(unsigned short* __restrict__ qbuf)
{
    const int g = blockIdx.x * 256 + threadIdx.x;   // < MTOT*32
    const int row = g >> 5;
    const int cg  = g & 31;                          // 8-channel chunk
    unsigned short* p = qbuf + (size_t)row * 256 + cg * 8;
    uint4 raw = *(const uint4*)p;
    unsigned short* rp = (unsigned short*)&raw;
    float v[8];
    #pragma unroll
    for (int j = 0; j < 8; ++j) v[j] = bf2f(rp[j]);
    float m = v[0];
    #pragma unroll
    for (int j = 1; j < 8; ++j) m = fmaxf(m, v[j]);
    m = fmaxf(m, __shfl_xor(m, 1, 64));
    m = fmaxf(m, __shfl_xor(m, 2, 64));
    float s = 0.0f;
    #pragma unroll
    for (int j = 0; j < 8; ++j) { v[j] = __expf(v[j] - m); s += v[j]; }
    s += __shfl_xor(s, 1, 64);
    s += __shfl_xor(s, 2, 64);
    const float r = 1.0f / s;
    #pragma unroll
    for (int j = 0; j < 8; ++j) rp[j] = f2bf(v[j] * r);
    *(uint4*)p = raw;
}

// ---------------------------------------------------------------------------
// ctx via MFMA, split-K, NO atomics.
// ---------------------------------------------------------------------------
__global__ __launch_bounds__(256) void ctx_mfma(
    const unsigned short* __restrict__ kvT,
    float* __restrict__ ctxp, float* __restrict__ skp)
{
    const int s = blockIdx.x, h = blockIdx.y, b = blockIdx.z;
    const int t = threadIdx.x, w = t >> 6, l = t & 63;
    const int fm = l & 15, fq = (l >> 4) * 8;
    const size_t rowA = (size_t)(b * 256 + h * 32 + fm) * NTOK;
    const int n0 = s * 512 + w * 128 + fq;
    const unsigned short* pa = kvT + rowA + n0;
    const unsigned short* pb = kvT + KVHALF + rowA + n0;

    f32x4 acc[2][2];
    #pragma unroll
    for (int x = 0; x < 2; ++x)
        #pragma unroll
        for (int y = 0; y < 2; ++y) acc[x][y] = (f32x4)0.0f;
    float ss0 = 0.0f, ss1 = 0.0f;

    #pragma unroll
    for (int step = 0; step < 4; ++step) {
        const int ko = step * 32;
        const uint4 ra0 = *(const uint4*)(pa + ko);
        const uint4 ra1 = *(const uint4*)(pa + (size_t)16 * NTOK + ko);
        const uint4 rb0 = *(const uint4*)(pb + ko);
        const uint4 rb1 = *(const uint4*)(pb + (size_t)16 * NTOK + ko);
        const bf16x8 a0 = *(const bf16x8*)&ra0;
        const bf16x8 a1 = *(const bf16x8*)&ra1;
        const bf16x8 b0 = *(const bf16x8*)&rb0;
        const bf16x8 b1 = *(const bf16x8*)&rb1;
        acc[0][0] = __builtin_amdgcn_mfma_f32_16x16x32_bf16(a0, b0, acc[0][0], 0, 0, 0);
        acc[0][1] = __builtin_amdgcn_mfma_f32_16x16x32_bf16(a0, b1, acc[0][1], 0, 0, 0);
        acc[1][0] = __builtin_amdgcn_mfma_f32_16x16x32_bf16(a1, b0, acc[1][0], 0, 0, 0);
        acc[1][1] = __builtin_amdgcn_mfma_f32_16x16x32_bf16(a1, b1, acc[1][1], 0, 0, 0);
        const unsigned short* u0 = (const unsigned short*)&ra0;
        const unsigned short* u1 = (const unsigned short*)&ra1;
        #pragma unroll
        for (int j = 0; j < 8; ++j) { ss0 += bf2f(u0[j]); ss1 += bf2f(u1[j]); }
    }

    ss0 += __shfl_xor(ss0, 16, 64); ss0 += __shfl_xor(ss0, 32, 64);
    ss1 += __shfl_xor(ss1, 16, 64); ss1 += __shfl_xor(ss1, 32, 64);
    __shared__ float skw[4][32];
    __shared__ float redc[4][32][33];
    if (l < 16) { skw[w][fm] = ss0; skw[w][16 + fm] = ss1; }

    const int rb4 = (l >> 4) * 4;
    #pragma unroll
    for (int x = 0; x < 2; ++x)
        #pragma unroll
        for (int y = 0; y < 2; ++y)
            #pragma unroll
            for (int r = 0; r < 4; ++r)
                redc[w][x * 16 + rb4 + r][y * 16 + fm] = acc[x][y][r];
    __syncthreads();

    if (t < 32)
        skp[(size_t)s * 512 + b * 256 + h * 32 + t] =
            skw[0][t] + skw[1][t] + skw[2][t] + skw[3][t];

    const int e0 = t * 4;
    const int dd = e0 >> 5, c0 = e0 & 31;
    float4 o;
    o.x = redc[0][dd][c0+0] + redc[1][dd][c0+0] + redc[2][dd][c0+0] + redc[3][dd][c0+0];
    o.y = redc[0][dd][c0+1] + redc[1][dd][c0+1] + redc[2][dd][c0+1] + redc[3][dd][c0+1];
    o.z = redc[0][dd][c0+2] + redc[1][dd][c0+2] + redc[2][dd][c0+2] + redc[3][dd][c0+2];
    o.w = redc[0][dd][c0+3] + redc[1][dd][c0+3] + redc[2][dd][c0+3] + redc[3][dd][c0+3];
    *(float4*)(ctxp + ((size_t)s * 16 + b * 8 + h) * 1024 + e0) = o;
}

// reduce split-K partials: ctx[16][1024] and Sk[512]. grid 66 x 256.
__global__ __launch_bounds__(256) void ctxred(
    const float* __restrict__ ctxp, const float* __restrict__ skp,
    float* __restrict__ ctx, float* __restrict__ Sk)
{
    const int o = blockIdx.x * 256 + threadIdx.x;   // 0..16895
    if (o < 16384) {
        float a = 0.0f;
        for (int s = 0; s < NSPLIT; ++s) a += ctxp[(size_t)s * 16384 + o];
        ctx[o] = a;
    } else {
        const int c = o - 16384;
        float a = 0.0f;
        for (int s = 0; s < NSPLIT; ++s) a += skp[(size_t)s * 512 + c];
        Sk[c] = a;
    }
}

// ---------------------------------------------------------------------------
// W'[b][n][h*32+d] = (1/sqrt(dk)) * (1/Sk[d]) * sum_e ctx[b][h][d][e] * Wo[h*32+e][n]
// ---------------------------------------------------------------------------
__global__ __launch_bounds__(256) void ctxwo_kernel(
    const float* __restrict__ ctx, const float* __restrict__ Sk,
    const unsigned short* __restrict__ wo_t, unsigned short* __restrict__ wp)
{
    const int h = blockIdx.x, b = blockIdx.y;
    const int n = threadIdx.x;
    __shared__ float cl[1024];
    __shared__ float sdk[32];
    {
        const float* cp = ctx + (size_t)(b * 8 + h) * 1024;
        *(float4*)&cl[n * 4] = *(const float4*)&cp[n * 4];
    }
    if (n < 32) sdk[n] = 0.17677669529663687f / Sk[b * 256 + h * 32 + n];
    __syncthreads();
    float w[32];
    const unsigned short* wop = wo_t + (size_t)n * 256 + h * 32;
    #pragma unroll
    for (int e = 0; e < 32; ++e) w[e] = bf2f(wop[e]);
    unsigned short outv[32];
    #pragma unroll
    for (int d = 0; d < 32; ++d) {
        float acc = 0.0f;
        #pragma unroll
        for (int e = 0; e < 32; ++e) acc += cl[d * 32 + e] * w[e];
        outv[d] = f2bf(acc * sdk[d]);
    }
    unsigned short* op = wp + (size_t)b * 65536 + (size_t)n * 256 + h * 32;
    #pragma unroll
    for (int d = 0; d < 32; d += 8)
        *(uint4*)(op + d) = *(uint4*)(outv + d);
}

// ---------------------------------------------------------------------------
// Vectorized LayerNorm: t = LN(t + add(bf16)) * g + b. 8 rows per block,
// one row per 32-lane group, 8 channels per lane (float4 x2 / short8 loads).
// No LDS, no barriers. WB: also write bf16 copy.
// ---------------------------------------------------------------------------
template<int WB>
__global__ __launch_bounds__(256) void ln8_kernel(
    float* __restrict__ t, const unsigned short* __restrict__ add,
    const float* __restrict__ g, const float* __restrict__ bta,
    unsigned short* __restrict__ tbf)
{
    const int l  = threadIdx.x & 31;
    const int rg = threadIdx.x >> 5;
    const size_t row = (size_t)blockIdx.x * 8 + rg;
    const size_t off = row * 256 + l * 8;

    const float4 a0 = *(const float4*)(t + off);
    const float4 a1 = *(const float4*)(t + off + 4);
    const uint4  ad = *(const uint4*)(add + off);
    const unsigned short* ap = (const unsigned short*)&ad;

    float v[8] = {a0.x, a0.y, a0.z, a0.w, a1.x, a1.y, a1.z, a1.w};
    float s = 0.0f;
    #pragma unroll
    for (int k = 0; k < 8; ++k) { v[k] += bf2f(ap[k]); s += v[k]; }
    #pragma unroll
    for (int o = 16; o; o >>= 1) s += __shfl_xor(s, o, 32);
    const float mu = s * (1.0f / 256.0f);

    float s2 = 0.0f;
    #pragma unroll
    for (int k = 0; k < 8; ++k) { v[k] -= mu; s2 += v[k] * v[k]; }
    #pragma unroll
    for (int o = 16; o; o >>= 1) s2 += __shfl_xor(s2, o, 32);
    const float rs = rsqrtf(s2 * (1.0f / 256.0f) + 1e-6f);

    const float4 g0 = *(const float4*)(g + l * 8);
    const float4 g1 = *(const float4*)(g + l * 8 + 4);
    const float4 b0 = *(const float4*)(bta + l * 8);
    const float4 b1 = *(const float4*)(bta + l * 8 + 4);
    const float gg[8] = {g0.x, g0.y, g0.z, g0.w, g1.x, g1.y, g1.z, g1.w};
    const float bb[8] = {b0.x, b0.y, b0.z, b0.w, b1.x, b1.y, b1.z, b1.w};

    float o8[8];
    #pragma unroll
    for (int k = 0; k < 8; ++k) o8[k] = v[k] * rs * gg[k] + bb[k];

    *(float4*)(t + off)     = make_float4(o8[0], o8[1], o8[2], o8[3]);
    *(float4*)(t + off + 4) = make_float4(o8[4], o8[5], o8[6], o8[7]);
    if (WB) {
        uint4 ob_;
        unsigned short* op = (unsigned short*)&ob_;
        #pragma unroll
        for (int k = 0; k < 8; ++k) op[k] = f2bf(o8[k]);
        *(uint4*)(tbf + off) = ob_;
    }
}

// ---------------------------------------------------------------------------
// depthwise 3x3x3 conv + residual, register-resident weights + sliding window.
// DEPTH-SPLIT: blockIdx.y = depth segment (12 planes each) -> 2x blocks
// resident (latency-bound fix: more wave-level MLP), depth loop fully
// unrolled so the compiler renames win[][] and hoists next-plane loads
// above current-plane FMAs.
// WB: 0 f32 out only, 1 f32 + bf16 copy, 2 = TRANSPOSED f32 out
//     (outp treated as [B][256][NTOK]; fuses the final tr_out).
// ---------------------------------------------------------------------------
#define DSEG 12
template<int WB>
__global__ __launch_bounds__(256) void posconv_kernel(
    const float* __restrict__ tin, const float* __restrict__ pw,
    const float* __restrict__ pb, float* __restrict__ outp,
    unsigned short* __restrict__ tbfp)
{
    const int hw  = blockIdx.x;           // 0..575
    const int d0  = blockIdx.y * DSEG;    // 0 or 12
    const int b   = blockIdx.z;
    const int hh = hw / 24, ww = hw % 24;
    const int c  = threadIdx.x;

    float w[27];
    #pragma unroll
    for (int k = 0; k < 27; ++k) w[k] = pw[c * 27 + k];
    const float bias = pb[c];

    const float* base = tin + (size_t)b * NTOK * 256 + c;

    const float* colp[9];
    bool colok[9];
    #pragma unroll
    for (int dh = -1; dh <= 1; ++dh)
        #pragma unroll
        for (int dw = -1; dw <= 1; ++dw) {
            const int j = (dh + 1) * 3 + (dw + 1);
            const int h2 = hh + dh, w2 = ww + dw;
            colok[j] = ((unsigned)h2 < 24u) & ((unsigned)w2 < 24u);
            colp[j] = base + (size_t)((h2 * 24 + w2) * 24 + d0) * 256;
        }

    float win[9][3];
    #pragma unroll
    for (int j = 0; j < 9; ++j) {
        win[j][0] = (colok[j] && d0 > 0) ? colp[j][-256] : 0.0f;  // halo plane
        win[j][1] = colok[j] ? colp[j][0] : 0.0f;
    }

    if constexpr (WB == 2) {
        float oseg[DSEG];
        #pragma unroll
        for (int dd = 0; dd < DSEG; ++dd) {
            #pragma unroll
            for (int j = 0; j < 9; ++j)
                win[j][2] = (colok[j] && (d0 + dd < 23)) ? colp[j][(dd + 1) * 256] : 0.0f;
            float acc = bias + win[4][1];
            #pragma unroll
            for (int j = 0; j < 9; ++j) {
                acc += w[j * 3 + 0] * win[j][0];
                acc += w[j * 3 + 1] * win[j][1];
                acc += w[j * 3 + 2] * win[j][2];
            }
            oseg[dd] = acc;
            #pragma unroll
            for (int j = 0; j < 9; ++j) { win[j][0] = win[j][1]; win[j][1] = win[j][2]; }
        }
        float* op = outp + ((size_t)b * 256 + c) * NTOK + hw * 24 + d0;
        #pragma unroll
        for (int q = 0; q < DSEG / 4; ++q)
            *(float4*)(op + q * 4) =
                make_float4(oseg[q*4], oseg[q*4+1], oseg[q*4+2], oseg[q*4+3]);
        return;
    }

    float* ob = outp + ((size_t)b * NTOK + (size_t)hw * 24 + d0) * 256 + c;
    unsigned short* tb = (WB == 1)
        ? (tbfp + ((size_t)b * NTOK + (size_t)hw * 24 + d0) * 256 + c)
        : (unsigned short*)nullptr;

    #pragma unroll
    for (int dd = 0; dd < DSEG; ++dd) {
        #pragma unroll
        for (int j = 0; j < 9; ++j)
            win[j][2] = (colok[j] && (d0 + dd < 23)) ? colp[j][(dd + 1) * 256] : 0.0f;

        float acc = bias + win[4][1];
        #pragma unroll
        for (int j = 0; j < 9; ++j) {
            acc += w[j * 3 + 0] * win[j][0];
            acc += w[j * 3 + 1] * win[j][1];
            acc += w[j * 3 + 2] * win[j][2];
        }
        ob[dd * 256] = acc;
        if (WB == 1) tb[dd * 256] = f2bf(acc);

        #pragma unroll
        for (int j = 0; j < 9; ++j) { win[j][0] = win[j][1]; win[j][1] = win[j][2]; }
    }
}

// ---------------------------------------------------------------------------
// launch
// ---------------------------------------------------------------------------
extern "C" void kernel_launch(void* const* d_in, const int* in_sizes, int n_in,
                              void* d_out, int out_size, void* d_ws, size_t ws_size,
                              hipStream_t stream)
{
    (void)in_sizes; (void)n_in; (void)out_size; (void)ws_size;
    const float* x     = (const float*)d_in[0];
    const float* Wx_w  = (const float*)d_in[1];
    const float* Wx_b  = (const float*)d_in[2];
    const float* Wq    = (const float*)d_in[3];
    const float* bq    = (const float*)d_in[4];
    const float* Wk    = (const float*)d_in[5];
    const float* bk    = (const float*)d_in[6];
    const float* Wv    = (const float*)d_in[7];
    const float* bv    = (const float*)d_in[8];
    const float* Wo    = (const float*)d_in[9];
    const float* bo    = (const float*)d_in[10];
    const float* ln1_g = (const float*)d_in[11];
    const float* ln1_b = (const float*)d_in[12];
    const float* ln2_g = (const float*)d_in[13];
    const float* ln2_b = (const float*)d_in[14];
    const float* fw1   = (const float*)d_in[15];
    const float* fb1   = (const float*)d_in[16];
    const float* fw2   = (const float*)d_in[17];
    const float* fb2   = (const float*)d_in[18];
    const float* pw    = (const float*)d_in[19];
    const float* pb    = (const float*)d_in[20];
    float* out = (float*)d_out;

    char* p = (char*)d_ws;
    float* tA            = (float*)p;          p += (size_t)MTOT * 256 * 4;
    float* tB            = (float*)p;          p += (size_t)MTOT * 256 * 4;
    unsigned short* tbf  = (unsigned short*)p; p += (size_t)MTOT * 256 * 2;
    unsigned short* qbuf = (unsigned short*)p; p += (size_t)MTOT * 256 * 2;
    unsigned short* hbf  = (unsigned short*)p; p += (size_t)MTOT * 512 * 2;   // also kvT
    unsigned short* ob   = (unsigned short*)p; p += (size_t)MTOT * 256 * 2;
    unsigned short* xbf  = (unsigned short*)p; p += (size_t)MTOT * 128 * 2;
    unsigned short* wqkv_t = (unsigned short*)p; p += (size_t)786432 * 2;
    unsigned short* wo_t   = (unsigned short*)p; p += (size_t)262144 * 2;
    unsigned short* w1_t   = (unsigned short*)p; p += (size_t)524288 * 2;
    unsigned short* w2_t   = (unsigned short*)p; p += (size_t)524288 * 2;
    unsigned short* wx_bf  = (unsigned short*)p; p += (size_t)32768 * 2;
    unsigned short* wp     = (unsigned short*)p; p += (size_t)BATCH * 65536 * 2;
    float* bqkv = (float*)p; p += 3072 * 4;
    float* ctx  = (float*)p; p += 16384 * 4;
    float* Sk   = (float*)p; p += 512 * 4;
    float* ctxp = (float*)p; p += (size_t)NSPLIT * 16384 * 4;
    float* skp  = (float*)p; p += (size_t)NSPLIT * 512 * 4;
    unsigned short* kvT = hbf;   // overlays FFN hidden (disjoint lifetime)

    hipLaunchKernelGGL(conv_weights, dim3(8333), dim3(256), 0, stream,
                       Wq, Wk, Wv, Wo, fw1, fw2, Wx_w, bq, bk, bv,
                       wqkv_t, wo_t, w1_t, w2_t, wx_bf, bqkv);
    hipLaunchKernelGGL(conv_x, dim3(NTOK / 32, CIN / 32, BATCH), dim3(256), 0, stream,
                       x, xbf);

    // input 1x1x1 conv + relu -> tA f32 + tbf bf16
    hipLaunchKernelGGL((gemm_bf16<1, 2>), dim3(216, 2, 1), dim3(256), 0, stream,
                       xbf, CIN, wx_bf, CIN, Wx_b, tA, tbf, 256, CIN,
                       (long)0, (long)0, (long)0);

    for (int i = 0; i < NLAYERS; ++i) {
        float* tin  = (i & 1) ? tB : tA;
        float* tout = (i & 1) ? tA : tB;

        // q projection: [M,256] x [256,256] -> qbuf
        hipLaunchKernelGGL((gemm_bf16<0, 1>), dim3(216, 2, 1), dim3(256), 0, stream,
                           tbf, 256, wqkv_t + (size_t)i * 196608, 256,
                           bqkv + i * 768, nullptr, qbuf, 256, 256,
                           (long)0, (long)0, (long)0);

        // k/v projection TRANSPOSED: A = W_kv [512][256], B = tbf [tok][256]
        // -> C[ch][tok] = exp(k)+bias / v+bias written straight into kvT.
        hipLaunchKernelGGL((gemm_bf16<3, 1>), dim3(4, 108, BATCH), dim3(256), 0, stream,
                           wqkv_t + (size_t)i * 196608 + 65536, 256,
                           tbf, 256, bqkv + i * 768 + 256,
                           nullptr, kvT, 0, 256,
                           (long)0, (long)NTOK * 256, (long)256 * NTOK);

        // ctx path: MFMA split-K -> reduce (no atomics, no memset)
        hipLaunchKernelGGL(ctx_mfma, dim3(NSPLIT, NHEAD, BATCH), dim3(256), 0, stream,
                           kvT, ctxp, skp);
        hipLaunchKernelGGL(ctxred, dim3(66), dim3(256), 0, stream, ctxp, skp, ctx, Sk);

        // q softmax in place + W' = (ctx/Sk) @ Wo (per batch)
        hipLaunchKernelGGL(qsm_kernel, dim3(3456), dim3(256), 0, stream, qbuf);
        hipLaunchKernelGGL(ctxwo_kernel, dim3(NHEAD, BATCH), dim3(256), 0, stream,
                           ctx, Sk, wo_t + (size_t)i * 65536, wp);

        // o_proj = qs @ W' + bo  (batched over z)
        hipLaunchKernelGGL((gemm_bf16<0, 1>), dim3(108, 2, BATCH), dim3(256), 0, stream,
                           qbuf, 256, wp, 256, bo + i * 256, nullptr, ob, 256, 256,
                           (long)NTOK * 256, (long)65536, (long)NTOK * 256);

        hipLaunchKernelGGL((ln8_kernel<1>), dim3(MTOT / 8), dim3(256), 0, stream,
                           tin, ob, ln1_g + i * 256, ln1_b + i * 256, tbf);

        // FFN (hbf free again: kvT consumed)
        hipLaunchKernelGGL((gemm_bf16<2, 1>), dim3(216, 4, 1), dim3(256), 0, stream,
                           tbf, 256, w1_t + (size_t)i * 131072, 256,
                           fb1 + i * 512, nullptr, hbf, 512, 256,
                           (long)0, (long)0, (long)0);
        hipLaunchKernelGGL((gemm_bf16<0, 1>), dim3(216, 2, 1), dim3(256), 0, stream,
                           hbf, 512, w2_t + (size_t)i * 131072, 512,
                           fb2 + i * 256, nullptr, ob, 256, 512,
                           (long)0, (long)0, (long)0);
        hipLaunchKernelGGL((ln8_kernel<0>), dim3(MTOT / 8), dim3(256), 0, stream,
                           tin, ob, ln2_g + i * 256, ln2_b + i * 256, nullptr);

        // depthwise conv + residual (depth-split); last layer writes
        // transposed into `out`
        if (i < NLAYERS - 1)
            hipLaunchKernelGGL((posconv_kernel<1>), dim3(576, 2, BATCH), dim3(256), 0, stream,
                               tin, pw + (size_t)i * 6912, pb + i * 256, tout, tbf);
        else
            hipLaunchKernelGGL((posconv_kernel<2>), dim3(576, 2, BATCH), dim3(256), 0, stream,
                               tin, pw + (size_t)i * 6912, pb + i * 256, out, nullptr);
    }
}